// Round 3
// baseline (3550.705 us; speedup 1.0000x reference)
//
#include <hip/hip_runtime.h>
#include <hip/hip_bf16.h>

// EfficientTransformerEncoder: B=32, D=256, L=1024, NH=8, DH=32, WIN=64, DFF=1024, NL=3.
// Inputs are fp32 (runtime-verified via detect_kernel); internal compute fp32;
// output written as fp32 (reference output dtype).
#define BSZ 32
#define DM 256
#define LSEQ 1024
#define MTOK (BSZ * LSEQ)   // 32768 tokens
#define NHEAD 8
#define DHEAD 32
#define WIN 64
#define DFF 1024

struct __align__(8) bh4 { __hip_bfloat16 x, y, z, w; };

// scalar dual-dtype load (element index)
__device__ __forceinline__ float ldx(const void* p, size_t idx, int bf) {
    return bf ? __bfloat162float(((const __hip_bfloat16*)p)[idx])
              : ((const float*)p)[idx];
}

// ---------------------------------------------------------------- detect ---
// Read even uint16 elements of features as bf16. True-bf16 data: all sane.
// fp32 data: these are mantissa bit-patterns -> random exponents -> crazy.
__global__ void detect_kernel(const void* __restrict__ F, int* __restrict__ flag)
{
    __shared__ int crazy;
    if (threadIdx.x == 0) crazy = 0;
    __syncthreads();
    const __hip_bfloat16* fb = (const __hip_bfloat16*)F;
    float v = __bfloat162float(fb[(size_t)threadIdx.x * 2]);
    if (!(fabsf(v) < 1000.0f)) atomicOr(&crazy, 1);   // catches NaN too
    __syncthreads();
    if (threadIdx.x == 0) *flag = crazy ? 0 : 1;      // 1 = bf16 inputs
}

// ---------------------------------------------------------------- embed ----
// X[m, c] = float(features[b, c, l]) + pe(l, c),  m = b*1024 + l
__global__ __launch_bounds__(256) void embed_kernel(
    const void* __restrict__ F, float* __restrict__ X, const int* __restrict__ flag)
{
    int bf = *flag;
    int m = blockIdx.x;            // token
    int c = threadIdx.x;           // channel
    int b = m >> 10, l = m & 1023;
    float f = ldx(F, ((size_t)(b * DM + c)) * LSEQ + l, bf);
    int i2 = c & ~1;               // even pair index
    float div = expf(-9.210340371976184f * (float)i2 / 256.0f);  // -ln(10000)
    float ang = (float)l * div;
    float pe = (c & 1) ? cosf(ang) : sinf(ang);
    X[(size_t)m * DM + c] = f + pe;
}

// ----------------------------------------------------------------- gemm ----
// C[m,n] = epilogue( sum_k A[m,k] * Bw[n,k] + bias[n] (+ resid[m,n]) )
// A fp32 [M,K]; Bw external dtype [N,K] (element offset woff); C fp32 [M,N].
__global__ __launch_bounds__(256) void gemm_kernel(
    const float* __restrict__ A, const void* __restrict__ Bw, size_t woff,
    const void* __restrict__ bias, size_t boff, const float* __restrict__ resid,
    float* __restrict__ C, int M, int N, int K, int gelu, const int* __restrict__ flag)
{
    __shared__ float As[16][65];
    __shared__ float Bs[16][65];
    int bf = *flag;
    int tid = threadIdx.x;
    int m0 = blockIdx.y * 64;
    int n0 = blockIdx.x * 64;
    int tx = tid & 15, ty = tid >> 4;
    int lr = tid >> 2;            // 0..63 row within tile
    int lk = (tid & 3) * 4;       // 0,4,8,12

    float acc[4][4] = {};

    for (int k0 = 0; k0 < K; k0 += 16) {
        const float* ap = A + (size_t)(m0 + lr) * K + k0 + lk;
        float4 av = *(const float4*)ap;
        As[lk + 0][lr] = av.x; As[lk + 1][lr] = av.y;
        As[lk + 2][lr] = av.z; As[lk + 3][lr] = av.w;
        size_t bidx = woff + (size_t)(n0 + lr) * K + k0 + lk;
        if (bf) {
            bh4 bv = *(const bh4*)((const __hip_bfloat16*)Bw + bidx);
            Bs[lk + 0][lr] = __bfloat162float(bv.x);
            Bs[lk + 1][lr] = __bfloat162float(bv.y);
            Bs[lk + 2][lr] = __bfloat162float(bv.z);
            Bs[lk + 3][lr] = __bfloat162float(bv.w);
        } else {
            float4 bv = *(const float4*)((const float*)Bw + bidx);
            Bs[lk + 0][lr] = bv.x; Bs[lk + 1][lr] = bv.y;
            Bs[lk + 2][lr] = bv.z; Bs[lk + 3][lr] = bv.w;
        }
        __syncthreads();
        #pragma unroll
        for (int k = 0; k < 16; ++k) {
            float a[4], b[4];
            #pragma unroll
            for (int i = 0; i < 4; ++i) a[i] = As[k][ty * 4 + i];
            #pragma unroll
            for (int j = 0; j < 4; ++j) b[j] = Bs[k][tx * 4 + j];
            #pragma unroll
            for (int i = 0; i < 4; ++i)
                #pragma unroll
                for (int j = 0; j < 4; ++j)
                    acc[i][j] += a[i] * b[j];
        }
        __syncthreads();
    }

    #pragma unroll
    for (int i = 0; i < 4; ++i) {
        int m = m0 + ty * 4 + i;
        #pragma unroll
        for (int j = 0; j < 4; ++j) {
            int n = n0 + tx * 4 + j;
            float v = acc[i][j] + ldx(bias, boff + n, bf);
            if (resid) v += resid[(size_t)m * N + n];
            if (gelu)  v = 0.5f * v * (1.0f + erff(v * 0.70710678118654752f));
            C[(size_t)m * N + n] = v;
        }
    }
}

// ------------------------------------------------------------ attention ----
// One wave per (window, head). QKV: [M, 768] fp32 (q | k | v). ATT: [M, 256].
__global__ __launch_bounds__(64) void attn_kernel(
    const float* __restrict__ QKV, float* __restrict__ ATT)
{
    int wg = blockIdx.x;               // global window id: b*16 + w
    int h  = blockIdx.y;               // head
    int base = wg * WIN;               // first token
    int t = threadIdx.x;               // query index within window

    __shared__ float ks[WIN][DHEAD + 1];
    __shared__ float vs[WIN][DHEAD + 1];

    const float scale = 0.17677669529663687f;   // 1/sqrt(32)
    const float* row = QKV + (size_t)(base + t) * 768;
    const float4* k4 = (const float4*)(row + 256 + h * DHEAD);
    const float4* v4 = (const float4*)(row + 512 + h * DHEAD);
    #pragma unroll
    for (int d4 = 0; d4 < 8; ++d4) {
        float4 kv = k4[d4];
        ks[t][d4 * 4 + 0] = kv.x; ks[t][d4 * 4 + 1] = kv.y;
        ks[t][d4 * 4 + 2] = kv.z; ks[t][d4 * 4 + 3] = kv.w;
        float4 vv = v4[d4];
        vs[t][d4 * 4 + 0] = vv.x; vs[t][d4 * 4 + 1] = vv.y;
        vs[t][d4 * 4 + 2] = vv.z; vs[t][d4 * 4 + 3] = vv.w;
    }
    float q[DHEAD];
    const float4* q4 = (const float4*)(row + h * DHEAD);
    #pragma unroll
    for (int d4 = 0; d4 < 8; ++d4) {
        float4 qv = q4[d4];
        q[d4 * 4 + 0] = qv.x * scale; q[d4 * 4 + 1] = qv.y * scale;
        q[d4 * 4 + 2] = qv.z * scale; q[d4 * 4 + 3] = qv.w * scale;
    }
    __syncthreads();

    float s[WIN];
    float mx = -1e30f;
    #pragma unroll
    for (int j = 0; j < WIN; ++j) {
        float a = 0.f;
        #pragma unroll
        for (int d = 0; d < DHEAD; ++d) a += q[d] * ks[j][d];
        s[j] = a;
        mx = fmaxf(mx, a);
    }
    float sum = 0.f;
    #pragma unroll
    for (int j = 0; j < WIN; ++j) { float e = __expf(s[j] - mx); s[j] = e; sum += e; }
    float inv = 1.0f / sum;
    float o[DHEAD] = {};
    #pragma unroll
    for (int j = 0; j < WIN; ++j) {
        float p = s[j] * inv;
        #pragma unroll
        for (int d = 0; d < DHEAD; ++d) o[d] += p * vs[j][d];
    }
    float* op = ATT + (size_t)(base + t) * DM + h * DHEAD;
    #pragma unroll
    for (int d = 0; d < DHEAD; ++d) op[d] = o[d];
}

// ------------------------------------------------------------ layernorm ----
// One wave per token (256 channels, 4/lane). O = LN(P)*scale + bias.
__global__ __launch_bounds__(256) void ln_kernel(
    const float* __restrict__ P, const void* __restrict__ sc, size_t soff,
    const void* __restrict__ bi, size_t boff, float* __restrict__ O,
    const int* __restrict__ flag)
{
    int bf = *flag;
    int wave = threadIdx.x >> 6;
    int lane = threadIdx.x & 63;
    int tok = blockIdx.x * 4 + wave;
    int c = lane * 4;
    const float* p = P + (size_t)tok * DM + c;
    float4 v = *(const float4*)p;
    float sm = v.x + v.y + v.z + v.w;
    float sq = v.x * v.x + v.y * v.y + v.z * v.z + v.w * v.w;
    #pragma unroll
    for (int off = 32; off > 0; off >>= 1) {
        sm += __shfl_down(sm, off);
        sq += __shfl_down(sq, off);
    }
    sm = __shfl(sm, 0); sq = __shfl(sq, 0);
    float mean = sm * (1.0f / 256.0f);
    float var  = sq * (1.0f / 256.0f) - mean * mean;
    float r = rsqrtf(var + 1e-5f);
    float4 o;
    o.x = (v.x - mean) * r * ldx(sc, soff + c + 0, bf) + ldx(bi, boff + c + 0, bf);
    o.y = (v.y - mean) * r * ldx(sc, soff + c + 1, bf) + ldx(bi, boff + c + 1, bf);
    o.z = (v.z - mean) * r * ldx(sc, soff + c + 2, bf) + ldx(bi, boff + c + 2, bf);
    o.w = (v.w - mean) * r * ldx(sc, soff + c + 3, bf) + ldx(bi, boff + c + 3, bf);
    *(float4*)(O + (size_t)tok * DM + c) = o;
}

// ------------------------------------------------------- output transpose --
// out[b, c, l] (fp32) = Xf[b*1024 + l, c], LDS-tiled 64x64.
__global__ __launch_bounds__(256) void out_kernel(
    const float* __restrict__ Xf, float* __restrict__ out)
{
    __shared__ float tile[64][65];
    int b  = blockIdx.z;
    int l0 = blockIdx.y * 64;
    int c0 = blockIdx.x * 64;
    int tid = threadIdx.x;
    int cin = tid & 63, lin = tid >> 6;
    #pragma unroll
    for (int it = 0; it < 16; ++it) {
        int l = lin + it * 4;
        tile[l][cin] = Xf[((size_t)(b * LSEQ + l0 + l)) * DM + c0 + cin];
    }
    __syncthreads();
    int lout = tid & 63, crow = tid >> 6;
    #pragma unroll
    for (int it = 0; it < 16; ++it) {
        int c = crow + it * 4;
        out[((size_t)(b * DM + c0 + c)) * LSEQ + l0 + lout] = tile[lout][c];
    }
}

// ----------------------------------------------------------------- driver --
extern "C" void kernel_launch(void* const* d_in, const int* in_sizes, int n_in,
                              void* d_out, int out_size, void* d_ws, size_t ws_size,
                              hipStream_t stream)
{
    const void* F   = d_in[0];
    const void* Wi  = d_in[1];
    const void* Bi  = d_in[2];
    const void* Wo  = d_in[3];
    const void* Bo  = d_in[4];
    const void* W1  = d_in[5];
    const void* B1  = d_in[6];
    const void* W2  = d_in[7];
    const void* B2  = d_in[8];
    const void* L1s = d_in[9];
    const void* L1b = d_in[10];
    const void* L2s = d_in[11];
    const void* L2b = d_in[12];
    const void* Fs  = d_in[13];
    const void* Fb  = d_in[14];

    // ws layout: flag(256B) | X [M,256] | BUF1 [M,1024] | BUF2 [M,256]  (~192 MB)
    int*   flag = (int*)d_ws;
    float* X    = (float*)((char*)d_ws + 256);
    float* BUF1 = X + (size_t)MTOK * DM;
    float* BUF2 = BUF1 + (size_t)MTOK * DFF;

    detect_kernel<<<1, 256, 0, stream>>>(F, flag);
    embed_kernel<<<MTOK, 256, 0, stream>>>(F, X, flag);

    for (int i = 0; i < 3; ++i) {
        // QKV = X @ Wi^T + bi        -> BUF1 [M, 768]
        gemm_kernel<<<dim3(768 / 64, MTOK / 64), 256, 0, stream>>>(
            X, Wi, (size_t)i * 768 * DM, Bi, (size_t)i * 768, nullptr, BUF1,
            MTOK, 768, DM, 0, flag);
        // windowed MHA               -> BUF2 [M, 256]
        attn_kernel<<<dim3(BSZ * (LSEQ / WIN), NHEAD), 64, 0, stream>>>(BUF1, BUF2);
        // P = ATT @ Wo^T + bo + X    -> BUF1 [M, 256]
        gemm_kernel<<<dim3(DM / 64, MTOK / 64), 256, 0, stream>>>(
            BUF2, Wo, (size_t)i * DM * DM, Bo, (size_t)i * DM, X, BUF1,
            MTOK, DM, DM, 0, flag);
        // X = LN(P)
        ln_kernel<<<MTOK / 4, 256, 0, stream>>>(
            BUF1, L1s, (size_t)i * DM, L1b, (size_t)i * DM, X, flag);
        // H = GELU(X @ W1^T + b1)    -> BUF1 [M, 1024]
        gemm_kernel<<<dim3(DFF / 64, MTOK / 64), 256, 0, stream>>>(
            X, W1, (size_t)i * DFF * DM, B1, (size_t)i * DFF, nullptr, BUF1,
            MTOK, DFF, DM, 1, flag);
        // P2 = H @ W2^T + b2 + X     -> BUF2 [M, 256]
        gemm_kernel<<<dim3(DM / 64, MTOK / 64), 256, 0, stream>>>(
            BUF1, W2, (size_t)i * DM * DFF, B2, (size_t)i * DM, X, BUF2,
            MTOK, DM, DFF, 0, flag);
        // X = LN(P2)
        ln_kernel<<<MTOK / 4, 256, 0, stream>>>(
            BUF2, L2s, (size_t)i * DM, L2b, (size_t)i * DM, X, flag);
    }

    // final LN -> BUF1, then transpose to [B, C, L] fp32
    ln_kernel<<<MTOK / 4, 256, 0, stream>>>(X, Fs, 0, Fb, 0, BUF1, flag);
    out_kernel<<<dim3(DM / 64, LSEQ / 64, BSZ), 256, 0, stream>>>(
        BUF1, (float*)d_out);
}

// Round 4
// 1712.267 us; speedup vs baseline: 2.0737x; 2.0737x over previous
//
#include <hip/hip_runtime.h>
#include <hip/hip_bf16.h>

// EfficientTransformerEncoder: B=32, D=256, L=1024, NH=8, DH=32, WIN=64, DFF=1024, NL=3.
// Inputs fp32 (runtime-verified); GEMMs via bf16 MFMA (fp32 accumulate); output fp32.
#define BSZ 32
#define DM 256
#define LSEQ 1024
#define MTOK (BSZ * LSEQ)   // 32768 tokens
#define NHEAD 8
#define DHEAD 32
#define WIN 64
#define DFF 1024

struct __align__(8) bh4 { __hip_bfloat16 x, y, z, w; };
typedef short bf16x8 __attribute__((ext_vector_type(8)));
typedef float f32x4 __attribute__((ext_vector_type(4)));

// scalar dual-dtype load (element index)
__device__ __forceinline__ float ldx(const void* p, size_t idx, int bf) {
    return bf ? __bfloat162float(((const __hip_bfloat16*)p)[idx])
              : ((const float*)p)[idx];
}

// ---------------------------------------------------------------- detect ---
__global__ void detect_kernel(const void* __restrict__ F, int* __restrict__ flag)
{
    __shared__ int crazy;
    if (threadIdx.x == 0) crazy = 0;
    __syncthreads();
    const __hip_bfloat16* fb = (const __hip_bfloat16*)F;
    float v = __bfloat162float(fb[(size_t)threadIdx.x * 2]);
    if (!(fabsf(v) < 1000.0f)) atomicOr(&crazy, 1);   // catches NaN too
    __syncthreads();
    if (threadIdx.x == 0) *flag = crazy ? 0 : 1;      // 1 = bf16 inputs
}

// ---------------------------------------------------------------- embed ----
__global__ __launch_bounds__(256) void embed_kernel(
    const void* __restrict__ F, float* __restrict__ X, const int* __restrict__ flag)
{
    int bf = *flag;
    int m = blockIdx.x;            // token
    int c = threadIdx.x;           // channel
    int b = m >> 10, l = m & 1023;
    float f = ldx(F, ((size_t)(b * DM + c)) * LSEQ + l, bf);
    int i2 = c & ~1;               // even pair index
    float div = expf(-9.210340371976184f * (float)i2 / 256.0f);  // -ln(10000)
    float ang = (float)l * div;
    float pe = (c & 1) ? cosf(ang) : sinf(ang);
    X[(size_t)m * DM + c] = f + pe;
}

// ------------------------------------------------------------ MFMA gemm ----
// C[m,n] = epi( sum_k A[m,k]*Bw[n,k] + bias[n] (+resid) ).  A fp32 [M,K];
// Bw [N,K] fp32-or-bf16; C fp32 [M,N].  Tile 128x128, BK=32, 4 waves,
// each wave 64x64 via 4x4 mfma_f32_16x16x32_bf16.  M,N %128==0, K %32==0.
__global__ __launch_bounds__(256) void gemm_mfma_kernel(
    const float* __restrict__ A, const void* __restrict__ Bw, size_t woff,
    const void* __restrict__ bias, size_t boff, const float* __restrict__ resid,
    float* __restrict__ C, int M, int N, int K, int gelu, const int* __restrict__ flag)
{
    // pitch 40 elems (80 B): row stride 20 banks -> 2-way (free) on frag reads
    __shared__ __hip_bfloat16 As[128][40];
    __shared__ __hip_bfloat16 Bs[128][40];
    const int bf = *flag;
    const int tid = threadIdx.x;
    const int lane = tid & 63, wave = tid >> 6;
    const int lane15 = lane & 15, quad = lane >> 4;
    const int wm = (wave & 1) * 64, wn = (wave >> 1) * 64;
    const int m0 = blockIdx.y * 128, n0 = blockIdx.x * 128;

    f32x4 acc[4][4] = {};

    for (int k0 = 0; k0 < K; k0 += 32) {
        // stage A: 128 rows x 32 k, fp32 -> bf16 (RNE)
        #pragma unroll
        for (int it = 0; it < 4; ++it) {
            int flat = it * 256 + tid;
            int row = flat >> 3, kc = (flat & 7) << 2;
            float4 av = *(const float4*)(A + (size_t)(m0 + row) * K + k0 + kc);
            bh4 h;
            h.x = __float2bfloat16(av.x); h.y = __float2bfloat16(av.y);
            h.z = __float2bfloat16(av.z); h.w = __float2bfloat16(av.w);
            *(bh4*)&As[row][kc] = h;
        }
        // stage B (weights): bf16 passthrough or fp32 -> bf16
        #pragma unroll
        for (int it = 0; it < 4; ++it) {
            int flat = it * 256 + tid;
            int row = flat >> 3, kc = (flat & 7) << 2;
            size_t idx = woff + (size_t)(n0 + row) * K + k0 + kc;
            bh4 h;
            if (bf) {
                h = *(const bh4*)((const __hip_bfloat16*)Bw + idx);
            } else {
                float4 bv = *(const float4*)((const float*)Bw + idx);
                h.x = __float2bfloat16(bv.x); h.y = __float2bfloat16(bv.y);
                h.z = __float2bfloat16(bv.z); h.w = __float2bfloat16(bv.w);
            }
            *(bh4*)&Bs[row][kc] = h;
        }
        __syncthreads();
        // fragments: A[m=lane15][k=quad*8+j], B[n=lane15][k=quad*8+j]
        bf16x8 af[4], bg[4];
        #pragma unroll
        for (int i = 0; i < 4; ++i)
            af[i] = *(const bf16x8*)&As[wm + i * 16 + lane15][quad * 8];
        #pragma unroll
        for (int j = 0; j < 4; ++j)
            bg[j] = *(const bf16x8*)&Bs[wn + j * 16 + lane15][quad * 8];
        #pragma unroll
        for (int i = 0; i < 4; ++i)
            #pragma unroll
            for (int j = 0; j < 4; ++j)
                acc[i][j] = __builtin_amdgcn_mfma_f32_16x16x32_bf16(
                    af[i], bg[j], acc[i][j], 0, 0, 0);
        __syncthreads();
    }

    // epilogue: D col = lane15, row = quad*4 + r  (m89-verified mapping)
    #pragma unroll
    for (int j = 0; j < 4; ++j) {
        int n = n0 + wn + j * 16 + lane15;
        float bb = ldx(bias, boff + n, bf);
        #pragma unroll
        for (int i = 0; i < 4; ++i) {
            int mbase = m0 + wm + i * 16 + quad * 4;
            #pragma unroll
            for (int r = 0; r < 4; ++r) {
                float v = acc[i][j][r] + bb;
                size_t off = (size_t)(mbase + r) * N + n;
                if (resid) v += resid[off];
                if (gelu)  v = 0.5f * v * (1.0f + erff(v * 0.70710678118654752f));
                C[off] = v;
            }
        }
    }
}

// ------------------------------------------------------------ attention ----
// One wave per (window, head). QKV: [M, 768] fp32 (q | k | v). ATT: [M, 256].
__global__ __launch_bounds__(64) void attn_kernel(
    const float* __restrict__ QKV, float* __restrict__ ATT)
{
    int wg = blockIdx.x;               // global window id: b*16 + w
    int h  = blockIdx.y;               // head
    int base = wg * WIN;               // first token
    int t = threadIdx.x;               // query index within window

    __shared__ float ks[WIN][DHEAD + 1];
    __shared__ float vs[WIN][DHEAD + 1];

    const float scale = 0.17677669529663687f;   // 1/sqrt(32)
    const float* row = QKV + (size_t)(base + t) * 768;
    const float4* k4 = (const float4*)(row + 256 + h * DHEAD);
    const float4* v4 = (const float4*)(row + 512 + h * DHEAD);
    #pragma unroll
    for (int d4 = 0; d4 < 8; ++d4) {
        float4 kv = k4[d4];
        ks[t][d4 * 4 + 0] = kv.x; ks[t][d4 * 4 + 1] = kv.y;
        ks[t][d4 * 4 + 2] = kv.z; ks[t][d4 * 4 + 3] = kv.w;
        float4 vv = v4[d4];
        vs[t][d4 * 4 + 0] = vv.x; vs[t][d4 * 4 + 1] = vv.y;
        vs[t][d4 * 4 + 2] = vv.z; vs[t][d4 * 4 + 3] = vv.w;
    }
    float q[DHEAD];
    const float4* q4 = (const float4*)(row + h * DHEAD);
    #pragma unroll
    for (int d4 = 0; d4 < 8; ++d4) {
        float4 qv = q4[d4];
        q[d4 * 4 + 0] = qv.x * scale; q[d4 * 4 + 1] = qv.y * scale;
        q[d4 * 4 + 2] = qv.z * scale; q[d4 * 4 + 3] = qv.w * scale;
    }
    __syncthreads();

    float s[WIN];
    float mx = -1e30f;
    #pragma unroll
    for (int j = 0; j < WIN; ++j) {
        float a = 0.f;
        #pragma unroll
        for (int d = 0; d < DHEAD; ++d) a += q[d] * ks[j][d];
        s[j] = a;
        mx = fmaxf(mx, a);
    }
    float sum = 0.f;
    #pragma unroll
    for (int j = 0; j < WIN; ++j) { float e = __expf(s[j] - mx); s[j] = e; sum += e; }
    float inv = 1.0f / sum;
    float o[DHEAD] = {};
    #pragma unroll
    for (int j = 0; j < WIN; ++j) {
        float p = s[j] * inv;
        #pragma unroll
        for (int d = 0; d < DHEAD; ++d) o[d] += p * vs[j][d];
    }
    float* op = ATT + (size_t)(base + t) * DM + h * DHEAD;
    #pragma unroll
    for (int d = 0; d < DHEAD; ++d) op[d] = o[d];
}

// ------------------------------------------------------------ layernorm ----
__global__ __launch_bounds__(256) void ln_kernel(
    const float* __restrict__ P, const void* __restrict__ sc, size_t soff,
    const void* __restrict__ bi, size_t boff, float* __restrict__ O,
    const int* __restrict__ flag)
{
    int bf = *flag;
    int wave = threadIdx.x >> 6;
    int lane = threadIdx.x & 63;
    int tok = blockIdx.x * 4 + wave;
    int c = lane * 4;
    const float* p = P + (size_t)tok * DM + c;
    float4 v = *(const float4*)p;
    float sm = v.x + v.y + v.z + v.w;
    float sq = v.x * v.x + v.y * v.y + v.z * v.z + v.w * v.w;
    #pragma unroll
    for (int off = 32; off > 0; off >>= 1) {
        sm += __shfl_down(sm, off);
        sq += __shfl_down(sq, off);
    }
    sm = __shfl(sm, 0); sq = __shfl(sq, 0);
    float mean = sm * (1.0f / 256.0f);
    float var  = sq * (1.0f / 256.0f) - mean * mean;
    float r = rsqrtf(var + 1e-5f);
    float4 o;
    o.x = (v.x - mean) * r * ldx(sc, soff + c + 0, bf) + ldx(bi, boff + c + 0, bf);
    o.y = (v.y - mean) * r * ldx(sc, soff + c + 1, bf) + ldx(bi, boff + c + 1, bf);
    o.z = (v.z - mean) * r * ldx(sc, soff + c + 2, bf) + ldx(bi, boff + c + 2, bf);
    o.w = (v.w - mean) * r * ldx(sc, soff + c + 3, bf) + ldx(bi, boff + c + 3, bf);
    *(float4*)(O + (size_t)tok * DM + c) = o;
}

// ------------------------------------------------------- output transpose --
__global__ __launch_bounds__(256) void out_kernel(
    const float* __restrict__ Xf, float* __restrict__ out)
{
    __shared__ float tile[64][65];
    int b  = blockIdx.z;
    int l0 = blockIdx.y * 64;
    int c0 = blockIdx.x * 64;
    int tid = threadIdx.x;
    int cin = tid & 63, lin = tid >> 6;
    #pragma unroll
    for (int it = 0; it < 16; ++it) {
        int l = lin + it * 4;
        tile[l][cin] = Xf[((size_t)(b * LSEQ + l0 + l)) * DM + c0 + cin];
    }
    __syncthreads();
    int lout = tid & 63, crow = tid >> 6;
    #pragma unroll
    for (int it = 0; it < 16; ++it) {
        int c = crow + it * 4;
        out[((size_t)(b * DM + c0 + c)) * LSEQ + l0 + lout] = tile[lout][c];
    }
}

// ----------------------------------------------------------------- driver --
extern "C" void kernel_launch(void* const* d_in, const int* in_sizes, int n_in,
                              void* d_out, int out_size, void* d_ws, size_t ws_size,
                              hipStream_t stream)
{
    const void* F   = d_in[0];
    const void* Wi  = d_in[1];
    const void* Bi  = d_in[2];
    const void* Wo  = d_in[3];
    const void* Bo  = d_in[4];
    const void* W1  = d_in[5];
    const void* B1  = d_in[6];
    const void* W2  = d_in[7];
    const void* B2  = d_in[8];
    const void* L1s = d_in[9];
    const void* L1b = d_in[10];
    const void* L2s = d_in[11];
    const void* L2b = d_in[12];
    const void* Fs  = d_in[13];
    const void* Fb  = d_in[14];

    // ws layout: flag(256B) | X [M,256] | BUF1 [M,1024] | BUF2 [M,256]
    int*   flag = (int*)d_ws;
    float* X    = (float*)((char*)d_ws + 256);
    float* BUF1 = X + (size_t)MTOK * DM;
    float* BUF2 = BUF1 + (size_t)MTOK * DFF;

    detect_kernel<<<1, 256, 0, stream>>>(F, flag);
    embed_kernel<<<MTOK, 256, 0, stream>>>(F, X, flag);

    for (int i = 0; i < 3; ++i) {
        // QKV = X @ Wi^T + bi        -> BUF1 [M, 768]
        gemm_mfma_kernel<<<dim3(768 / 128, MTOK / 128), 256, 0, stream>>>(
            X, Wi, (size_t)i * 768 * DM, Bi, (size_t)i * 768, nullptr, BUF1,
            MTOK, 768, DM, 0, flag);
        // windowed MHA               -> BUF2 [M, 256]
        attn_kernel<<<dim3(BSZ * (LSEQ / WIN), NHEAD), 64, 0, stream>>>(BUF1, BUF2);
        // P = ATT @ Wo^T + bo + X    -> BUF1 [M, 256]
        gemm_mfma_kernel<<<dim3(DM / 128, MTOK / 128), 256, 0, stream>>>(
            BUF2, Wo, (size_t)i * DM * DM, Bo, (size_t)i * DM, X, BUF1,
            MTOK, DM, DM, 0, flag);
        // X = LN(P)
        ln_kernel<<<MTOK / 4, 256, 0, stream>>>(
            BUF1, L1s, (size_t)i * DM, L1b, (size_t)i * DM, X, flag);
        // H = GELU(X @ W1^T + b1)    -> BUF1 [M, 1024]
        gemm_mfma_kernel<<<dim3(DFF / 128, MTOK / 128), 256, 0, stream>>>(
            X, W1, (size_t)i * DFF * DM, B1, (size_t)i * DFF, nullptr, BUF1,
            MTOK, DFF, DM, 1, flag);
        // P2 = H @ W2^T + b2 + X     -> BUF2 [M, 256]
        gemm_mfma_kernel<<<dim3(DM / 128, MTOK / 128), 256, 0, stream>>>(
            BUF1, W2, (size_t)i * DM * DFF, B2, (size_t)i * DM, X, BUF2,
            MTOK, DM, DFF, 0, flag);
        // X = LN(P2)
        ln_kernel<<<MTOK / 4, 256, 0, stream>>>(
            BUF2, L2s, (size_t)i * DM, L2b, (size_t)i * DM, X, flag);
    }

    // final LN -> BUF1, then transpose to [B, C, L] fp32
    ln_kernel<<<MTOK / 4, 256, 0, stream>>>(X, Fs, 0, Fb, 0, BUF1, flag);
    out_kernel<<<dim3(DM / 64, LSEQ / 64, BSZ), 256, 0, stream>>>(
        BUF1, (float*)d_out);
}

// Round 5
// 905.136 us; speedup vs baseline: 3.9228x; 1.8917x over previous
//
#include <hip/hip_runtime.h>
#include <hip/hip_bf16.h>

// EfficientTransformerEncoder: B=32, D=256, L=1024, NH=8, DH=32, WIN=64, DFF=1024, NL=3.
// Inputs fp32; GEMMs bf16-MFMA (m97 structure: global_load_lds dwordx4 staging,
// 128x128 tile, BK=32, LDS-transposed coalesced epilogue); fp32 accumulate/LN; out fp32.
#define BSZ 32
#define DM 256
#define LSEQ 1024
#define MTOK (BSZ * LSEQ)   // 32768 tokens
#define NHEAD 8
#define DHEAD 32
#define WIN 64
#define DFF 1024

typedef short bf16x8 __attribute__((ext_vector_type(8)));
typedef float f32x4 __attribute__((ext_vector_type(4)));
typedef unsigned short u16x8 __attribute__((ext_vector_type(8)));

union BF { __hip_bfloat16 h; unsigned short u; };
__device__ __forceinline__ unsigned short f2bf(float f) { BF b; b.h = __float2bfloat16(f); return b.u; }
__device__ __forceinline__ float bf2f(unsigned short u) { return __uint_as_float((unsigned)u << 16); }

#define GLD_LDS16(gp, lp) __builtin_amdgcn_global_load_lds( \
    (const __attribute__((address_space(1))) void*)(gp),    \
    (__attribute__((address_space(3))) void*)(lp), 16, 0, 0)

// ------------------------------------------------------------- weight cvt --
// fp32 -> bf16, 4 elems/thread. n % 1024 == 0.
__global__ __launch_bounds__(256) void cvt_kernel(
    const float* __restrict__ s, unsigned short* __restrict__ d, int n)
{
    int i = (blockIdx.x * 256 + threadIdx.x) * 4;
    if (i >= n) return;
    float4 v = *(const float4*)(s + i);
    ushort4 o = { f2bf(v.x), f2bf(v.y), f2bf(v.z), f2bf(v.w) };
    *(ushort4*)(d + i) = o;
}

// -------------------------------------------------------------- PE table ---
__global__ __launch_bounds__(256) void pe_kernel(float* __restrict__ PE)
{
    int l = blockIdx.x, c = threadIdx.x;
    int i2 = c & ~1;
    float div = expf(-9.210340371976184f * (float)i2 / 256.0f);  // -ln(10000)
    float ang = (float)l * div;
    PE[l * DM + c] = (c & 1) ? cosf(ang) : sinf(ang);
}

// ---------------------------------------------------------------- embed ----
// Xf/Xb[b*1024+l, c] = F[b, c, l] + PE[l, c]; LDS-tiled transpose, coalesced both sides.
__global__ __launch_bounds__(256) void embed_kernel(
    const float* __restrict__ F, const float* __restrict__ PE,
    float* __restrict__ Xf, unsigned short* __restrict__ Xb)
{
    __shared__ float tile[64][65];
    int b = blockIdx.z, l0 = blockIdx.y * 64, c0 = blockIdx.x * 64;
    int tid = threadIdx.x;
    int li = tid & 63, c4 = tid >> 6;
    #pragma unroll
    for (int it = 0; it < 16; ++it) {
        int c = c4 + it * 4;
        tile[c][li] = F[((size_t)(b * DM + c0 + c)) * LSEQ + l0 + li];
    }
    __syncthreads();
    int ci = tid & 63, l4 = tid >> 6;
    #pragma unroll
    for (int it = 0; it < 16; ++it) {
        int l = l4 + it * 4;
        float x = tile[ci][l] + PE[(l0 + l) * DM + c0 + ci];
        size_t off = ((size_t)b * LSEQ + l0 + l) * DM + c0 + ci;
        Xf[off] = x;
        Xb[off] = f2bf(x);
    }
}

// ------------------------------------------------------------ MFMA gemm ----
// C[m,n] = epi( sum_k A[m,k]*Bw[n,k] + bias[n] (+resid) ).
// A,Bw bf16 [*,K]; bias/resid fp32; outputs Cf fp32 and/or Cb bf16.
// Tile 128x128, BK=32, 4 waves (2x2 of 64x64), 4x4 mfma_f32_16x16x32_bf16.
__global__ __launch_bounds__(256) void gemm_mfma_kernel(
    const unsigned short* __restrict__ A, const unsigned short* __restrict__ Bw,
    const float* __restrict__ bias, const float* __restrict__ resid,
    float* __restrict__ Cf, unsigned short* __restrict__ Cb,
    int M, int N, int K, int gelu)
{
    __shared__ __align__(16) char smem[17408];
    unsigned short* As = (unsigned short*)smem;           // 128x32 bf16 = 8 KB
    unsigned short* Bs = (unsigned short*)(smem + 8192);  // 8 KB

    const int tid = threadIdx.x;
    const int lane = tid & 63, wave = tid >> 6;
    const int lane15 = lane & 15, quad = lane >> 4;
    const int wm = (wave & 1) * 64, wn = (wave >> 1) * 64;
    const int m0 = blockIdx.y * 128, n0 = blockIdx.x * 128;

    // staging coords: thread t covers 8 bf16 (16 B); round r adds 64 rows
    const int srow = tid >> 2, scol = (tid & 3) * 8;

    f32x4 acc[4][4] = {};

    for (int k0 = 0; k0 < K; k0 += 32) {
        GLD_LDS16(A + (size_t)(m0 + srow) * K + k0 + scol,        As + tid * 8);
        GLD_LDS16(A + (size_t)(m0 + 64 + srow) * K + k0 + scol,   As + 2048 + tid * 8);
        GLD_LDS16(Bw + (size_t)(n0 + srow) * K + k0 + scol,       Bs + tid * 8);
        GLD_LDS16(Bw + (size_t)(n0 + 64 + srow) * K + k0 + scol,  Bs + 2048 + tid * 8);
        __syncthreads();   // compiler drains vmcnt before s_barrier

        bf16x8 af[4], bg[4];
        #pragma unroll
        for (int i = 0; i < 4; ++i)
            af[i] = *(const bf16x8*)(As + (wm + i * 16 + lane15) * 32 + quad * 8);
        #pragma unroll
        for (int j = 0; j < 4; ++j)
            bg[j] = *(const bf16x8*)(Bs + (wn + j * 16 + lane15) * 32 + quad * 8);
        #pragma unroll
        for (int i = 0; i < 4; ++i)
            #pragma unroll
            for (int j = 0; j < 4; ++j)
                acc[i][j] = __builtin_amdgcn_mfma_f32_16x16x32_bf16(
                    af[i], bg[j], acc[i][j], 0, 0, 0);
        __syncthreads();
    }

    // epilogue: wave-private LDS transpose (pitch 68 floats -> conflict-light),
    // then coalesced 64B/lane stores. D layout: col=lane15, row=quad*4+r.
    float* Es = (float*)(smem + wave * 4352);   // 16 rows x 68 floats
    const int r16 = lane >> 2;            // output row within 16-block
    const int cg  = (lane & 3) * 16;      // col group base
    #pragma unroll
    for (int i = 0; i < 4; ++i) {
        #pragma unroll
        for (int j = 0; j < 4; ++j)
            #pragma unroll
            for (int r = 0; r < 4; ++r)
                Es[(quad * 4 + r) * 68 + j * 16 + lane15] = acc[i][j][r];
        asm volatile("s_waitcnt lgkmcnt(0)" ::: "memory");  // wave-private: no barrier

        int m = m0 + wm + i * 16 + r16;
        int nb = n0 + wn + cg;
        size_t gbase = (size_t)m * N + nb;
        float v[16];
        #pragma unroll
        for (int c = 0; c < 4; ++c) {
            f32x4 t = *(const f32x4*)&Es[r16 * 68 + cg + c * 4];
            v[c * 4 + 0] = t[0]; v[c * 4 + 1] = t[1];
            v[c * 4 + 2] = t[2]; v[c * 4 + 3] = t[3];
        }
        #pragma unroll
        for (int c = 0; c < 4; ++c) {
            float4 bb = *(const float4*)(bias + nb + c * 4);
            v[c * 4 + 0] += bb.x; v[c * 4 + 1] += bb.y;
            v[c * 4 + 2] += bb.z; v[c * 4 + 3] += bb.w;
        }
        if (resid) {
            #pragma unroll
            for (int c = 0; c < 4; ++c) {
                float4 rr = *(const float4*)(resid + gbase + c * 4);
                v[c * 4 + 0] += rr.x; v[c * 4 + 1] += rr.y;
                v[c * 4 + 2] += rr.z; v[c * 4 + 3] += rr.w;
            }
        }
        if (gelu) {
            #pragma unroll
            for (int e = 0; e < 16; ++e)
                v[e] = 0.5f * v[e] * (1.0f + erff(v[e] * 0.70710678118654752f));
        }
        if (Cf) {
            #pragma unroll
            for (int c = 0; c < 4; ++c) {
                float4 o = { v[c * 4 + 0], v[c * 4 + 1], v[c * 4 + 2], v[c * 4 + 3] };
                *(float4*)(Cf + gbase + c * 4) = o;
            }
        }
        if (Cb) {
            #pragma unroll
            for (int c = 0; c < 2; ++c) {
                uint4 o;
                o.x = f2bf(v[c * 8 + 0]) | ((unsigned)f2bf(v[c * 8 + 1]) << 16);
                o.y = f2bf(v[c * 8 + 2]) | ((unsigned)f2bf(v[c * 8 + 3]) << 16);
                o.z = f2bf(v[c * 8 + 4]) | ((unsigned)f2bf(v[c * 8 + 5]) << 16);
                o.w = f2bf(v[c * 8 + 6]) | ((unsigned)f2bf(v[c * 8 + 7]) << 16);
                *(uint4*)(Cb + gbase + c * 8) = o;
            }
        }
        asm volatile("" ::: "memory");  // keep Es reads before next i's writes
    }
}

// ------------------------------------------------------------ attention ----
// One wave per (window, head). QKV bf16 [M,768] (q|k|v). ATT bf16 [M,256].
__global__ __launch_bounds__(64) void attn_kernel(
    const unsigned short* __restrict__ QKV, unsigned short* __restrict__ ATT)
{
    int wg = blockIdx.x;               // b*16 + w
    int h  = blockIdx.y;               // head
    int base = wg * WIN;
    int t = threadIdx.x;               // query index

    __shared__ float ks[WIN][DHEAD + 1];
    __shared__ float vs[WIN][DHEAD + 1];

    const float scale = 0.17677669529663687f;   // 1/sqrt(32)
    const unsigned short* row = QKV + (size_t)(base + t) * 768;
    #pragma unroll
    for (int d8 = 0; d8 < 4; ++d8) {
        u16x8 kv = *(const u16x8*)(row + 256 + h * DHEAD + d8 * 8);
        u16x8 vv = *(const u16x8*)(row + 512 + h * DHEAD + d8 * 8);
        #pragma unroll
        for (int e = 0; e < 8; ++e) {
            ks[t][d8 * 8 + e] = bf2f(kv[e]);
            vs[t][d8 * 8 + e] = bf2f(vv[e]);
        }
    }
    float q[DHEAD];
    #pragma unroll
    for (int d8 = 0; d8 < 4; ++d8) {
        u16x8 qv = *(const u16x8*)(row + h * DHEAD + d8 * 8);
        #pragma unroll
        for (int e = 0; e < 8; ++e) q[d8 * 8 + e] = bf2f(qv[e]) * scale;
    }
    __syncthreads();

    float s[WIN];
    float mx = -1e30f;
    #pragma unroll
    for (int j = 0; j < WIN; ++j) {
        float a = 0.f;
        #pragma unroll
        for (int d = 0; d < DHEAD; ++d) a += q[d] * ks[j][d];
        s[j] = a;
        mx = fmaxf(mx, a);
    }
    float sum = 0.f;
    #pragma unroll
    for (int j = 0; j < WIN; ++j) { float e = __expf(s[j] - mx); s[j] = e; sum += e; }
    float inv = 1.0f / sum;
    float o[DHEAD] = {};
    #pragma unroll
    for (int j = 0; j < WIN; ++j) {
        float p = s[j] * inv;
        #pragma unroll
        for (int d = 0; d < DHEAD; ++d) o[d] += p * vs[j][d];
    }
    unsigned short* op = ATT + (size_t)(base + t) * DM + h * DHEAD;
    #pragma unroll
    for (int c = 0; c < 4; ++c) {
        uint2 pk;
        pk.x = f2bf(o[c * 8 + 0]) | ((unsigned)f2bf(o[c * 8 + 1]) << 16);
        pk.y = f2bf(o[c * 8 + 2]) | ((unsigned)f2bf(o[c * 8 + 3]) << 16);
        uint2 pk2;
        pk2.x = f2bf(o[c * 8 + 4]) | ((unsigned)f2bf(o[c * 8 + 5]) << 16);
        pk2.y = f2bf(o[c * 8 + 6]) | ((unsigned)f2bf(o[c * 8 + 7]) << 16);
        uint4 w = { pk.x, pk.y, pk2.x, pk2.y };
        *(uint4*)(op + c * 8) = w;
    }
}

// ------------------------------------------------------------ layernorm ----
// One wave per token. Of fp32 (+ optional Ob bf16) = LN(P)*sc + bi.
__global__ __launch_bounds__(256) void ln_kernel(
    const float* __restrict__ P, const float* __restrict__ sc,
    const float* __restrict__ bi, float* __restrict__ Of,
    unsigned short* __restrict__ Ob)
{
    int wave = threadIdx.x >> 6;
    int lane = threadIdx.x & 63;
    int tok = blockIdx.x * 4 + wave;
    int c = lane * 4;
    float4 v = *(const float4*)(P + (size_t)tok * DM + c);
    float sm = v.x + v.y + v.z + v.w;
    float sq = v.x * v.x + v.y * v.y + v.z * v.z + v.w * v.w;
    #pragma unroll
    for (int off = 32; off > 0; off >>= 1) {
        sm += __shfl_down(sm, off);
        sq += __shfl_down(sq, off);
    }
    sm = __shfl(sm, 0); sq = __shfl(sq, 0);
    float mean = sm * (1.0f / 256.0f);
    float var  = sq * (1.0f / 256.0f) - mean * mean;
    float r = rsqrtf(var + 1e-5f);
    float4 s4 = *(const float4*)(sc + c);
    float4 b4 = *(const float4*)(bi + c);
    float4 o;
    o.x = (v.x - mean) * r * s4.x + b4.x;
    o.y = (v.y - mean) * r * s4.y + b4.y;
    o.z = (v.z - mean) * r * s4.z + b4.z;
    o.w = (v.w - mean) * r * s4.w + b4.w;
    *(float4*)(Of + (size_t)tok * DM + c) = o;
    if (Ob) {
        uint2 pk;
        pk.x = f2bf(o.x) | ((unsigned)f2bf(o.y) << 16);
        pk.y = f2bf(o.z) | ((unsigned)f2bf(o.w) << 16);
        *(uint2*)(Ob + (size_t)tok * DM + c) = pk;
    }
}

// ------------------------------------------------------- output transpose --
__global__ __launch_bounds__(256) void out_kernel(
    const float* __restrict__ Xf, float* __restrict__ out)
{
    __shared__ float tile[64][65];
    int b  = blockIdx.z;
    int l0 = blockIdx.y * 64;
    int c0 = blockIdx.x * 64;
    int tid = threadIdx.x;
    int cin = tid & 63, lin = tid >> 6;
    #pragma unroll
    for (int it = 0; it < 16; ++it) {
        int l = lin + it * 4;
        tile[l][cin] = Xf[((size_t)(b * LSEQ + l0 + l)) * DM + c0 + cin];
    }
    __syncthreads();
    int lout = tid & 63, crow = tid >> 6;
    #pragma unroll
    for (int it = 0; it < 16; ++it) {
        int c = crow + it * 4;
        out[((size_t)(b * DM + c0 + c)) * LSEQ + l0 + lout] = tile[lout][c];
    }
}

// ----------------------------------------------------------------- driver --
extern "C" void kernel_launch(void* const* d_in, const int* in_sizes, int n_in,
                              void* d_out, int out_size, void* d_ws, size_t ws_size,
                              hipStream_t stream)
{
    const float* F   = (const float*)d_in[0];
    const float* Wi  = (const float*)d_in[1];
    const float* Bi  = (const float*)d_in[2];
    const float* Wo  = (const float*)d_in[3];
    const float* Bo  = (const float*)d_in[4];
    const float* W1  = (const float*)d_in[5];
    const float* B1  = (const float*)d_in[6];
    const float* W2  = (const float*)d_in[7];
    const float* B2  = (const float*)d_in[8];
    const float* L1s = (const float*)d_in[9];
    const float* L1b = (const float*)d_in[10];
    const float* L2s = (const float*)d_in[11];
    const float* L2b = (const float*)d_in[12];
    const float* Fs  = (const float*)d_in[13];
    const float* Fb  = (const float*)d_in[14];

    // ws layout (bytes):
    char* w = (char*)d_ws;
    float*          Xf   = (float*)w;                              // 33.5 MB
    float*          Pf   = (float*)(w + 33554432);                 // fp32 view, aliases QKVb
    unsigned short* QKVb = (unsigned short*)(w + 33554432);        // 50 MB (bf16 [M,768])
    unsigned short* Hb   = (unsigned short*)(w + 83886080);        // 67 MB (bf16 [M,1024])
    unsigned short* Xb   = (unsigned short*)(w + 150994944);       // 16.8 MB
    unsigned short* ATTb = (unsigned short*)(w + 167772160);       // 16.8 MB
    unsigned short* WB   = (unsigned short*)(w + 184549376);       // 4.7 MB weights bf16
    float*          PE   = (float*)(w + 189267968);                // 1 MB
    unsigned short* Wib  = WB;                                     // 3*768*256
    unsigned short* Wob  = WB + 589824;                            // 3*256*256
    unsigned short* W1b  = WB + 786432;                            // 3*1024*256
    unsigned short* W2b  = WB + 1572864;                           // 3*256*1024

    cvt_kernel<<<589824 / 1024, 256, 0, stream>>>(Wi, Wib, 589824);
    cvt_kernel<<<196608 / 1024, 256, 0, stream>>>(Wo, Wob, 196608);
    cvt_kernel<<<786432 / 1024, 256, 0, stream>>>(W1, W1b, 786432);
    cvt_kernel<<<786432 / 1024, 256, 0, stream>>>(W2, W2b, 786432);
    pe_kernel<<<LSEQ, 256, 0, stream>>>(PE);
    embed_kernel<<<dim3(DM / 64, LSEQ / 64, BSZ), 256, 0, stream>>>(F, PE, Xf, Xb);

    for (int i = 0; i < 3; ++i) {
        // QKV = X @ Wi^T + bi -> QKVb (bf16)
        gemm_mfma_kernel<<<dim3(768 / 128, MTOK / 128), 256, 0, stream>>>(
            Xb, Wib + (size_t)i * 196608, Bi + i * 768, nullptr,
            nullptr, QKVb, MTOK, 768, DM, 0);
        // windowed MHA -> ATTb (bf16)
        attn_kernel<<<dim3(BSZ * (LSEQ / WIN), NHEAD), 64, 0, stream>>>(QKVb, ATTb);
        // P = ATT @ Wo^T + bo + X -> Pf (fp32; aliases QKVb, already consumed)
        gemm_mfma_kernel<<<dim3(DM / 128, MTOK / 128), 256, 0, stream>>>(
            ATTb, Wob + (size_t)i * 65536, Bo + i * DM, Xf,
            Pf, nullptr, MTOK, DM, DM, 0);
        // X = LN1(P) -> Xf + Xb
        ln_kernel<<<MTOK / 4, 256, 0, stream>>>(
            Pf, L1s + i * DM, L1b + i * DM, Xf, Xb);
        // H = GELU(X @ W1^T + b1) -> Hb (bf16)
        gemm_mfma_kernel<<<dim3(DFF / 128, MTOK / 128), 256, 0, stream>>>(
            Xb, W1b + (size_t)i * 262144, B1 + i * DFF, nullptr,
            nullptr, Hb, MTOK, DFF, DM, 1);
        // P2 = H @ W2^T + b2 + X -> Pf
        gemm_mfma_kernel<<<dim3(DM / 128, MTOK / 128), 256, 0, stream>>>(
            Hb, W2b + (size_t)i * 262144, B2 + i * DM, Xf,
            Pf, nullptr, MTOK, DM, DFF, 0);
        // X = LN2(P2) -> Xf + Xb
        ln_kernel<<<MTOK / 4, 256, 0, stream>>>(
            Pf, L2s + i * DM, L2b + i * DM, Xf, Xb);
    }

    // final LN -> Pf, transpose to [B, C, L] fp32
    ln_kernel<<<MTOK / 4, 256, 0, stream>>>(Xf, Fs, Fb, Pf, nullptr);
    out_kernel<<<dim3(DM / 64, LSEQ / 64, BSZ), 256, 0, stream>>>(
        Pf, (float*)d_out);
}

// Round 6
// 728.961 us; speedup vs baseline: 4.8709x; 1.2417x over previous
//
#include <hip/hip_runtime.h>
#include <hip/hip_bf16.h>

// EfficientTransformerEncoder: B=32, D=256, L=1024, NH=8, DH=32, WIN=64, DFF=1024, NL=3.
// Inputs fp32; GEMMs + attention via bf16 MFMA (fp32 accumulate); out fp32.
#define BSZ 32
#define DM 256
#define LSEQ 1024
#define MTOK (BSZ * LSEQ)   // 32768 tokens
#define NHEAD 8
#define DHEAD 32
#define WIN 64
#define DFF 1024

typedef short bf16x8 __attribute__((ext_vector_type(8)));
typedef float f32x4 __attribute__((ext_vector_type(4)));
typedef unsigned short u16x8 __attribute__((ext_vector_type(8)));

union BF { __hip_bfloat16 h; unsigned short u; };
__device__ __forceinline__ unsigned short f2bf(float f) { BF b; b.h = __float2bfloat16(f); return b.u; }
__device__ __forceinline__ float bf2f(unsigned short u) { return __uint_as_float((unsigned)u << 16); }

#define GLD_LDS16(gp, lp) __builtin_amdgcn_global_load_lds( \
    (const __attribute__((address_space(1))) void*)(gp),    \
    (__attribute__((address_space(3))) void*)(lp), 16, 0, 0)

// ------------------------------------------------------------- weight cvt --
__global__ __launch_bounds__(256) void cvt_kernel(
    const float* __restrict__ s, unsigned short* __restrict__ d, int n)
{
    int i = (blockIdx.x * 256 + threadIdx.x) * 4;
    if (i >= n) return;
    float4 v = *(const float4*)(s + i);
    ushort4 o = { f2bf(v.x), f2bf(v.y), f2bf(v.z), f2bf(v.w) };
    *(ushort4*)(d + i) = o;
}

// -------------------------------------------------------------- PE table ---
__global__ __launch_bounds__(256) void pe_kernel(float* __restrict__ PE)
{
    int l = blockIdx.x, c = threadIdx.x;
    int i2 = c & ~1;
    float div = expf(-9.210340371976184f * (float)i2 / 256.0f);  // -ln(10000)
    float ang = (float)l * div;
    PE[l * DM + c] = (c & 1) ? cosf(ang) : sinf(ang);
}

// ---------------------------------------------------------------- embed ----
__global__ __launch_bounds__(256) void embed_kernel(
    const float* __restrict__ F, const float* __restrict__ PE,
    float* __restrict__ Xf, unsigned short* __restrict__ Xb)
{
    __shared__ float tile[64][65];
    int b = blockIdx.z, l0 = blockIdx.y * 64, c0 = blockIdx.x * 64;
    int tid = threadIdx.x;
    int li = tid & 63, c4 = tid >> 6;
    #pragma unroll
    for (int it = 0; it < 16; ++it) {
        int c = c4 + it * 4;
        tile[c][li] = F[((size_t)(b * DM + c0 + c)) * LSEQ + l0 + li];
    }
    __syncthreads();
    int ci = tid & 63, l4 = tid >> 6;
    #pragma unroll
    for (int it = 0; it < 16; ++it) {
        int l = l4 + it * 4;
        float x = tile[ci][l] + PE[(l0 + l) * DM + c0 + ci];
        size_t off = ((size_t)b * LSEQ + l0 + l) * DM + c0 + ci;
        Xf[off] = x;
        Xb[off] = f2bf(x);
    }
}

// ------------------------------------------------------------ MFMA gemm ----
// (unchanged from round 5 — validated)
__global__ __launch_bounds__(256) void gemm_mfma_kernel(
    const unsigned short* __restrict__ A, const unsigned short* __restrict__ Bw,
    const float* __restrict__ bias, const float* __restrict__ resid,
    float* __restrict__ Cf, unsigned short* __restrict__ Cb,
    int M, int N, int K, int gelu)
{
    __shared__ __align__(16) char smem[17408];
    unsigned short* As = (unsigned short*)smem;
    unsigned short* Bs = (unsigned short*)(smem + 8192);

    const int tid = threadIdx.x;
    const int lane = tid & 63, wave = tid >> 6;
    const int lane15 = lane & 15, quad = lane >> 4;
    const int wm = (wave & 1) * 64, wn = (wave >> 1) * 64;
    const int m0 = blockIdx.y * 128, n0 = blockIdx.x * 128;
    const int srow = tid >> 2, scol = (tid & 3) * 8;

    f32x4 acc[4][4] = {};

    for (int k0 = 0; k0 < K; k0 += 32) {
        GLD_LDS16(A + (size_t)(m0 + srow) * K + k0 + scol,        As + tid * 8);
        GLD_LDS16(A + (size_t)(m0 + 64 + srow) * K + k0 + scol,   As + 2048 + tid * 8);
        GLD_LDS16(Bw + (size_t)(n0 + srow) * K + k0 + scol,       Bs + tid * 8);
        GLD_LDS16(Bw + (size_t)(n0 + 64 + srow) * K + k0 + scol,  Bs + 2048 + tid * 8);
        __syncthreads();

        bf16x8 af[4], bg[4];
        #pragma unroll
        for (int i = 0; i < 4; ++i)
            af[i] = *(const bf16x8*)(As + (wm + i * 16 + lane15) * 32 + quad * 8);
        #pragma unroll
        for (int j = 0; j < 4; ++j)
            bg[j] = *(const bf16x8*)(Bs + (wn + j * 16 + lane15) * 32 + quad * 8);
        #pragma unroll
        for (int i = 0; i < 4; ++i)
            #pragma unroll
            for (int j = 0; j < 4; ++j)
                acc[i][j] = __builtin_amdgcn_mfma_f32_16x16x32_bf16(
                    af[i], bg[j], acc[i][j], 0, 0, 0);
        __syncthreads();
    }

    float* Es = (float*)(smem + wave * 4352);   // 16 rows x 68 floats
    const int r16 = lane >> 2;
    const int cg  = (lane & 3) * 16;
    #pragma unroll
    for (int i = 0; i < 4; ++i) {
        #pragma unroll
        for (int j = 0; j < 4; ++j)
            #pragma unroll
            for (int r = 0; r < 4; ++r)
                Es[(quad * 4 + r) * 68 + j * 16 + lane15] = acc[i][j][r];
        asm volatile("s_waitcnt lgkmcnt(0)" ::: "memory");

        int m = m0 + wm + i * 16 + r16;
        int nb = n0 + wn + cg;
        size_t gbase = (size_t)m * N + nb;
        float v[16];
        #pragma unroll
        for (int c = 0; c < 4; ++c) {
            f32x4 t = *(const f32x4*)&Es[r16 * 68 + cg + c * 4];
            v[c * 4 + 0] = t[0]; v[c * 4 + 1] = t[1];
            v[c * 4 + 2] = t[2]; v[c * 4 + 3] = t[3];
        }
        #pragma unroll
        for (int c = 0; c < 4; ++c) {
            float4 bb = *(const float4*)(bias + nb + c * 4);
            v[c * 4 + 0] += bb.x; v[c * 4 + 1] += bb.y;
            v[c * 4 + 2] += bb.z; v[c * 4 + 3] += bb.w;
        }
        if (resid) {
            #pragma unroll
            for (int c = 0; c < 4; ++c) {
                float4 rr = *(const float4*)(resid + gbase + c * 4);
                v[c * 4 + 0] += rr.x; v[c * 4 + 1] += rr.y;
                v[c * 4 + 2] += rr.z; v[c * 4 + 3] += rr.w;
            }
        }
        if (gelu) {
            #pragma unroll
            for (int e = 0; e < 16; ++e)
                v[e] = 0.5f * v[e] * (1.0f + erff(v[e] * 0.70710678118654752f));
        }
        if (Cf) {
            #pragma unroll
            for (int c = 0; c < 4; ++c) {
                float4 o = { v[c * 4 + 0], v[c * 4 + 1], v[c * 4 + 2], v[c * 4 + 3] };
                *(float4*)(Cf + gbase + c * 4) = o;
            }
        }
        if (Cb) {
            #pragma unroll
            for (int c = 0; c < 2; ++c) {
                uint4 o;
                o.x = f2bf(v[c * 8 + 0]) | ((unsigned)f2bf(v[c * 8 + 1]) << 16);
                o.y = f2bf(v[c * 8 + 2]) | ((unsigned)f2bf(v[c * 8 + 3]) << 16);
                o.z = f2bf(v[c * 8 + 4]) | ((unsigned)f2bf(v[c * 8 + 5]) << 16);
                o.w = f2bf(v[c * 8 + 6]) | ((unsigned)f2bf(v[c * 8 + 7]) << 16);
                *(uint4*)(Cb + gbase + c * 8) = o;
            }
        }
        asm volatile("" ::: "memory");
    }
}

// ------------------------------------------------------- MFMA attention ----
// One wave per (window, head). S=QK^T via 16 MFMA, reg softmax, P->LDS, PV via
// 16 MFMA, LDS-transposed coalesced output. QKV bf16 [M,768]; ATT bf16 [M,256].
__global__ __launch_bounds__(64) void attn_mfma_kernel(
    const unsigned short* __restrict__ QKV, unsigned short* __restrict__ ATT)
{
    __shared__ __align__(16) char smem[22016];
    unsigned short* Qs = (unsigned short*)smem;           // [t][d] 64x32, 4 KB
    unsigned short* Ks = (unsigned short*)(smem + 4096);  // [t][d] 64x32, 4 KB
    unsigned short* VT = (unsigned short*)(smem + 8192);  // [d][t] 32 x pitch72
    unsigned short* Ps = (unsigned short*)(smem + 12800); // [q][k] 64 x pitch72
    float*          Po = (float*)(smem + 12800);          // [q][d] 64 x pitch36 (alias)

    const int wg = blockIdx.x, h = blockIdx.y;
    const int base = wg * WIN;
    const int lane = threadIdx.x;
    const int l15 = lane & 15, quad = lane >> 4;
    const float scale = 0.17677669529663687f;   // 1/sqrt(32)

    const unsigned short* qkv = QKV + (size_t)base * 768;

    // stage Q, K via async 16B chunks; V via VGPR + LDS transpose
    #pragma unroll
    for (int rr = 0; rr < 4; ++rr) {
        int chunk = rr * 64 + lane;            // 0..255
        int t = chunk >> 2, c4 = chunk & 3;
        GLD_LDS16(qkv + (size_t)t * 768 + h * 32 + c4 * 8,       Qs + (size_t)chunk * 8);
        GLD_LDS16(qkv + (size_t)t * 768 + 256 + h * 32 + c4 * 8, Ks + (size_t)chunk * 8);
    }
    u16x8 vv[4];
    #pragma unroll
    for (int cc = 0; cc < 4; ++cc)
        vv[cc] = *(const u16x8*)(qkv + (size_t)lane * 768 + 512 + h * 32 + cc * 8);
    #pragma unroll
    for (int cc = 0; cc < 4; ++cc)
        #pragma unroll
        for (int e = 0; e < 8; ++e)
            VT[(cc * 8 + e) * 72 + lane] = vv[cc][e];
    __syncthreads();   // drains vmcnt (global_load_lds) + lgkm (VT writes)

    // S = Q K^T : tiles i (query) x j (key)
    const f32x4 zero4 = {0.f, 0.f, 0.f, 0.f};
    bf16x8 aq[4], bk[4];
    #pragma unroll
    for (int i = 0; i < 4; ++i)
        aq[i] = *(const bf16x8*)(Qs + (i * 16 + l15) * 32 + quad * 8);
    #pragma unroll
    for (int j = 0; j < 4; ++j)
        bk[j] = *(const bf16x8*)(Ks + (j * 16 + l15) * 32 + quad * 8);
    f32x4 S[4][4];
    #pragma unroll
    for (int i = 0; i < 4; ++i)
        #pragma unroll
        for (int j = 0; j < 4; ++j)
            S[i][j] = __builtin_amdgcn_mfma_f32_16x16x32_bf16(aq[i], bk[j], zero4, 0, 0, 0);

    // softmax over keys: rows m=i*16+quad*4+r (lane-local), cols j*16+l15.
    float mx[4][4], sum[4][4];
    #pragma unroll
    for (int i = 0; i < 4; ++i)
        #pragma unroll
        for (int r = 0; r < 4; ++r) {
            float m0 = -1e30f;
            #pragma unroll
            for (int j = 0; j < 4; ++j) {
                S[i][j][r] *= scale;
                m0 = fmaxf(m0, S[i][j][r]);
            }
            mx[i][r] = m0;
        }
    #pragma unroll
    for (int off = 1; off < 16; off <<= 1)
        #pragma unroll
        for (int i = 0; i < 4; ++i)
            #pragma unroll
            for (int r = 0; r < 4; ++r)
                mx[i][r] = fmaxf(mx[i][r], __shfl_xor(mx[i][r], off));
    #pragma unroll
    for (int i = 0; i < 4; ++i)
        #pragma unroll
        for (int r = 0; r < 4; ++r) {
            float s0 = 0.f;
            #pragma unroll
            for (int j = 0; j < 4; ++j) {
                float e = __expf(S[i][j][r] - mx[i][r]);
                S[i][j][r] = e;
                s0 += e;
            }
            sum[i][r] = s0;
        }
    #pragma unroll
    for (int off = 1; off < 16; off <<= 1)
        #pragma unroll
        for (int i = 0; i < 4; ++i)
            #pragma unroll
            for (int r = 0; r < 4; ++r)
                sum[i][r] += __shfl_xor(sum[i][r], off);

    // P (bf16, normalized) -> LDS in A-operand layout [q][k]
    #pragma unroll
    for (int i = 0; i < 4; ++i)
        #pragma unroll
        for (int r = 0; r < 4; ++r) {
            float inv = 1.0f / sum[i][r];
            #pragma unroll
            for (int j = 0; j < 4; ++j)
                Ps[(i * 16 + quad * 4 + r) * 72 + j * 16 + l15] =
                    f2bf(S[i][j][r] * inv);
        }
    asm volatile("s_waitcnt lgkmcnt(0)" ::: "memory");

    // O = P V : m-tiles i (query), n-tiles jd (dhead 0..1), K=64 (2 chunks)
    bf16x8 ap0[4], ap1[4], bv0[2], bv1[2];
    #pragma unroll
    for (int i = 0; i < 4; ++i) {
        ap0[i] = *(const bf16x8*)(Ps + (i * 16 + l15) * 72 + quad * 8);
        ap1[i] = *(const bf16x8*)(Ps + (i * 16 + l15) * 72 + 32 + quad * 8);
    }
    #pragma unroll
    for (int jd = 0; jd < 2; ++jd) {
        bv0[jd] = *(const bf16x8*)(VT + (jd * 16 + l15) * 72 + quad * 8);
        bv1[jd] = *(const bf16x8*)(VT + (jd * 16 + l15) * 72 + 32 + quad * 8);
    }
    f32x4 O[4][2];
    #pragma unroll
    for (int i = 0; i < 4; ++i)
        #pragma unroll
        for (int jd = 0; jd < 2; ++jd) {
            f32x4 t = __builtin_amdgcn_mfma_f32_16x16x32_bf16(ap0[i], bv0[jd], zero4, 0, 0, 0);
            O[i][jd] = __builtin_amdgcn_mfma_f32_16x16x32_bf16(ap1[i], bv1[jd], t, 0, 0, 0);
        }
    asm volatile("s_waitcnt lgkmcnt(0)" ::: "memory");   // Ps reads done before overwrite

    // transpose O via LDS (aliases Ps region), then 64B/lane coalesced stores
    #pragma unroll
    for (int i = 0; i < 4; ++i)
        #pragma unroll
        for (int jd = 0; jd < 2; ++jd)
            #pragma unroll
            for (int r = 0; r < 4; ++r)
                Po[(i * 16 + quad * 4 + r) * 36 + jd * 16 + l15] = O[i][jd][r];
    asm volatile("s_waitcnt lgkmcnt(0)" ::: "memory");

    unsigned short* op = ATT + (size_t)(base + lane) * DM + h * 32;
    #pragma unroll
    for (int g = 0; g < 4; ++g) {
        f32x4 t0 = *(const f32x4*)(Po + lane * 36 + g * 8);
        f32x4 t1 = *(const f32x4*)(Po + lane * 36 + g * 8 + 4);
        uint4 w;
        w.x = f2bf(t0[0]) | ((unsigned)f2bf(t0[1]) << 16);
        w.y = f2bf(t0[2]) | ((unsigned)f2bf(t0[3]) << 16);
        w.z = f2bf(t1[0]) | ((unsigned)f2bf(t1[1]) << 16);
        w.w = f2bf(t1[2]) | ((unsigned)f2bf(t1[3]) << 16);
        *(uint4*)(op + g * 8) = w;
    }
}

// ------------------------------------------------------------ layernorm ----
__global__ __launch_bounds__(256) void ln_kernel(
    const float* __restrict__ P, const float* __restrict__ sc,
    const float* __restrict__ bi, float* __restrict__ Of,
    unsigned short* __restrict__ Ob)
{
    int wave = threadIdx.x >> 6;
    int lane = threadIdx.x & 63;
    int tok = blockIdx.x * 4 + wave;
    int c = lane * 4;
    float4 v = *(const float4*)(P + (size_t)tok * DM + c);
    float sm = v.x + v.y + v.z + v.w;
    float sq = v.x * v.x + v.y * v.y + v.z * v.z + v.w * v.w;
    #pragma unroll
    for (int off = 32; off > 0; off >>= 1) {
        sm += __shfl_down(sm, off);
        sq += __shfl_down(sq, off);
    }
    sm = __shfl(sm, 0); sq = __shfl(sq, 0);
    float mean = sm * (1.0f / 256.0f);
    float var  = sq * (1.0f / 256.0f) - mean * mean;
    float r = rsqrtf(var + 1e-5f);
    float4 s4 = *(const float4*)(sc + c);
    float4 b4 = *(const float4*)(bi + c);
    float4 o;
    o.x = (v.x - mean) * r * s4.x + b4.x;
    o.y = (v.y - mean) * r * s4.y + b4.y;
    o.z = (v.z - mean) * r * s4.z + b4.z;
    o.w = (v.w - mean) * r * s4.w + b4.w;
    *(float4*)(Of + (size_t)tok * DM + c) = o;
    if (Ob) {
        uint2 pk;
        pk.x = f2bf(o.x) | ((unsigned)f2bf(o.y) << 16);
        pk.y = f2bf(o.z) | ((unsigned)f2bf(o.w) << 16);
        *(uint2*)(Ob + (size_t)tok * DM + c) = pk;
    }
}

// ---------------------------------------------- final LN + transpose out ---
// block: 64 tokens x 256 channels. Phase 1: per-token LN stats; phase 2:
// 4x (64x64 LDS tile, LN applied at load) transposed coalesced store.
__global__ __launch_bounds__(256) void out_ln_kernel(
    const float* __restrict__ Xf, const float* __restrict__ sc,
    const float* __restrict__ bi, float* __restrict__ out)
{
    __shared__ float mean_s[64], rinv_s[64];
    __shared__ float tile[64][65];
    int b = blockIdx.y, l0 = blockIdx.x * 64;
    int tid = threadIdx.x, wave = tid >> 6, lane = tid & 63;
    int c = lane * 4;
    #pragma unroll
    for (int it = 0; it < 16; ++it) {
        int tl = wave * 16 + it;
        float4 v = *(const float4*)(Xf + ((size_t)(b * LSEQ + l0 + tl)) * DM + c);
        float sm = v.x + v.y + v.z + v.w;
        float sq = v.x * v.x + v.y * v.y + v.z * v.z + v.w * v.w;
        #pragma unroll
        for (int off = 32; off > 0; off >>= 1) {
            sm += __shfl_down(sm, off);
            sq += __shfl_down(sq, off);
        }
        if (lane == 0) {
            float mean = sm * (1.0f / 256.0f);
            float var  = sq * (1.0f / 256.0f) - mean * mean;
            mean_s[tl] = mean;
            rinv_s[tl] = rsqrtf(var + 1e-5f);
        }
    }
    __syncthreads();
    #pragma unroll
    for (int ct = 0; ct < 4; ++ct) {
        int c0 = ct * 64;
        int cin = tid & 63, lin = tid >> 6;
        #pragma unroll
        for (int it = 0; it < 16; ++it) {
            int l = lin + it * 4;
            float v = Xf[((size_t)(b * LSEQ + l0 + l)) * DM + c0 + cin];
            tile[l][cin] = (v - mean_s[l]) * rinv_s[l] * sc[c0 + cin] + bi[c0 + cin];
        }
        __syncthreads();
        int lout = tid & 63, crow = tid >> 6;
        #pragma unroll
        for (int it = 0; it < 16; ++it) {
            int cc = crow + it * 4;
            out[((size_t)(b * DM + c0 + cc)) * LSEQ + l0 + lout] = tile[lout][cc];
        }
        __syncthreads();
    }
}

// ----------------------------------------------------------------- driver --
extern "C" void kernel_launch(void* const* d_in, const int* in_sizes, int n_in,
                              void* d_out, int out_size, void* d_ws, size_t ws_size,
                              hipStream_t stream)
{
    const float* F   = (const float*)d_in[0];
    const float* Wi  = (const float*)d_in[1];
    const float* Bi  = (const float*)d_in[2];
    const float* Wo  = (const float*)d_in[3];
    const float* Bo  = (const float*)d_in[4];
    const float* W1  = (const float*)d_in[5];
    const float* B1  = (const float*)d_in[6];
    const float* W2  = (const float*)d_in[7];
    const float* B2  = (const float*)d_in[8];
    const float* L1s = (const float*)d_in[9];
    const float* L1b = (const float*)d_in[10];
    const float* L2s = (const float*)d_in[11];
    const float* L2b = (const float*)d_in[12];
    const float* Fs  = (const float*)d_in[13];
    const float* Fb  = (const float*)d_in[14];

    char* w = (char*)d_ws;
    float*          Xf   = (float*)w;                              // 33.5 MB
    float*          Pf   = (float*)(w + 33554432);                 // aliases QKVb
    unsigned short* QKVb = (unsigned short*)(w + 33554432);        // 50 MB
    unsigned short* Hb   = (unsigned short*)(w + 83886080);        // 67 MB
    unsigned short* Xb   = (unsigned short*)(w + 150994944);       // 16.8 MB
    unsigned short* ATTb = (unsigned short*)(w + 167772160);       // 16.8 MB
    unsigned short* WB   = (unsigned short*)(w + 184549376);       // 4.7 MB
    float*          PE   = (float*)(w + 189267968);                // 1 MB
    unsigned short* Wib  = WB;
    unsigned short* Wob  = WB + 589824;
    unsigned short* W1b  = WB + 786432;
    unsigned short* W2b  = WB + 1572864;

    cvt_kernel<<<589824 / 1024, 256, 0, stream>>>(Wi, Wib, 589824);
    cvt_kernel<<<196608 / 1024, 256, 0, stream>>>(Wo, Wob, 196608);
    cvt_kernel<<<786432 / 1024, 256, 0, stream>>>(W1, W1b, 786432);
    cvt_kernel<<<786432 / 1024, 256, 0, stream>>>(W2, W2b, 786432);
    pe_kernel<<<LSEQ, 256, 0, stream>>>(PE);
    embed_kernel<<<dim3(DM / 64, LSEQ / 64, BSZ), 256, 0, stream>>>(F, PE, Xf, Xb);

    for (int i = 0; i < 3; ++i) {
        gemm_mfma_kernel<<<dim3(768 / 128, MTOK / 128), 256, 0, stream>>>(
            Xb, Wib + (size_t)i * 196608, Bi + i * 768, nullptr,
            nullptr, QKVb, MTOK, 768, DM, 0);
        attn_mfma_kernel<<<dim3(BSZ * (LSEQ / WIN), NHEAD), 64, 0, stream>>>(QKVb, ATTb);
        gemm_mfma_kernel<<<dim3(DM / 128, MTOK / 128), 256, 0, stream>>>(
            ATTb, Wob + (size_t)i * 65536, Bo + i * DM, Xf,
            Pf, nullptr, MTOK, DM, DM, 0);
        ln_kernel<<<MTOK / 4, 256, 0, stream>>>(
            Pf, L1s + i * DM, L1b + i * DM, Xf, Xb);
        gemm_mfma_kernel<<<dim3(DFF / 128, MTOK / 128), 256, 0, stream>>>(
            Xb, W1b + (size_t)i * 262144, B1 + i * DFF, nullptr,
            nullptr, Hb, MTOK, DFF, DM, 1);
        gemm_mfma_kernel<<<dim3(DM / 128, MTOK / 128), 256, 0, stream>>>(
            Hb, W2b + (size_t)i * 262144, B2 + i * DM, Xf,
            Pf, nullptr, MTOK, DM, DFF, 0);
        ln_kernel<<<MTOK / 4, 256, 0, stream>>>(
            Pf, L2s + i * DM, L2b + i * DM, Xf, Xb);
    }

    out_ln_kernel<<<dim3(LSEQ / 64, BSZ), 256, 0, stream>>>(
        Xf, Fs, Fb, (float*)d_out);
}

// Round 7
// 698.877 us; speedup vs baseline: 5.0806x; 1.0430x over previous
//
#include <hip/hip_runtime.h>
#include <hip/hip_bf16.h>

// EfficientTransformerEncoder: B=32, D=256, L=1024, NH=8, DH=32, WIN=64, DFF=1024, NL=3.
// Inputs fp32; GEMMs + attention via bf16 MFMA (fp32 accumulate); LN fused into
// N=256 GEMMs; out fp32.
#define BSZ 32
#define DM 256
#define LSEQ 1024
#define MTOK (BSZ * LSEQ)   // 32768 tokens
#define NHEAD 8
#define DHEAD 32
#define WIN 64
#define DFF 1024

typedef short bf16x8 __attribute__((ext_vector_type(8)));
typedef float f32x4 __attribute__((ext_vector_type(4)));
typedef unsigned short u16x8 __attribute__((ext_vector_type(8)));

union BF { __hip_bfloat16 h; unsigned short u; };
__device__ __forceinline__ unsigned short f2bf(float f) { BF b; b.h = __float2bfloat16(f); return b.u; }
__device__ __forceinline__ float bf2f(unsigned short u) { return __uint_as_float((unsigned)u << 16); }

#define GLD_LDS16(gp, lp) __builtin_amdgcn_global_load_lds( \
    (const __attribute__((address_space(1))) void*)(gp),    \
    (__attribute__((address_space(3))) void*)(lp), 16, 0, 0)

// tanh-form GELU: x * sigmoid(2*0.79788456*(x + 0.044715 x^3)); |err| vs erf-GELU < ~2e-3
__device__ __forceinline__ float gelu_fast(float x) {
    float t = x * (0.7978845608f + 0.0356774081f * x * x);
    return x / (1.0f + __expf(-2.0f * t));
}

// ------------------------------------------------------------- weight cvt --
__global__ __launch_bounds__(256) void cvt_kernel(
    const float* __restrict__ s, unsigned short* __restrict__ d, int n)
{
    int i = (blockIdx.x * 256 + threadIdx.x) * 4;
    if (i >= n) return;
    float4 v = *(const float4*)(s + i);
    ushort4 o = { f2bf(v.x), f2bf(v.y), f2bf(v.z), f2bf(v.w) };
    *(ushort4*)(d + i) = o;
}

// -------------------------------------------------------------- PE table ---
__global__ __launch_bounds__(256) void pe_kernel(float* __restrict__ PE)
{
    int l = blockIdx.x, c = threadIdx.x;
    int i2 = c & ~1;
    float div = expf(-9.210340371976184f * (float)i2 / 256.0f);  // -ln(10000)
    float ang = (float)l * div;
    PE[l * DM + c] = (c & 1) ? cosf(ang) : sinf(ang);
}

// ---------------------------------------------------------------- embed ----
__global__ __launch_bounds__(256) void embed_kernel(
    const float* __restrict__ F, const float* __restrict__ PE,
    float* __restrict__ Xf, unsigned short* __restrict__ Xb)
{
    __shared__ float tile[64][65];
    int b = blockIdx.z, l0 = blockIdx.y * 64, c0 = blockIdx.x * 64;
    int tid = threadIdx.x;
    int li = tid & 63, c4 = tid >> 6;
    #pragma unroll
    for (int it = 0; it < 16; ++it) {
        int c = c4 + it * 4;
        tile[c][li] = F[((size_t)(b * DM + c0 + c)) * LSEQ + l0 + li];
    }
    __syncthreads();
    int ci = tid & 63, l4 = tid >> 6;
    #pragma unroll
    for (int it = 0; it < 16; ++it) {
        int l = l4 + it * 4;
        float x = tile[ci][l] + PE[(l0 + l) * DM + c0 + ci];
        size_t off = ((size_t)b * LSEQ + l0 + l) * DM + c0 + ci;
        Xf[off] = x;
        Xb[off] = f2bf(x);
    }
}

// ------------------------------------------------------------ MFMA gemm ----
// Grid (M/128, N/128): M-tiles fastest -> blocks sharing A rows land on the
// same XCD (linear_id % 8 constant) -> A fetched ~once per XCD.
__global__ __launch_bounds__(256) void gemm_mfma_kernel(
    const unsigned short* __restrict__ A, const unsigned short* __restrict__ Bw,
    const float* __restrict__ bias,
    unsigned short* __restrict__ Cb, int M, int N, int K, int gelu)
{
    __shared__ __align__(16) char smem[17408];
    unsigned short* As = (unsigned short*)smem;
    unsigned short* Bs = (unsigned short*)(smem + 8192);

    const int tid = threadIdx.x;
    const int lane = tid & 63, wave = tid >> 6;
    const int lane15 = lane & 15, quad = lane >> 4;
    const int wm = (wave & 1) * 64, wn = (wave >> 1) * 64;
    const int m0 = blockIdx.x * 128, n0 = blockIdx.y * 128;
    const int srow = tid >> 2, scol = (tid & 3) * 8;

    f32x4 acc[4][4] = {};

    for (int k0 = 0; k0 < K; k0 += 32) {
        GLD_LDS16(A + (size_t)(m0 + srow) * K + k0 + scol,        As + tid * 8);
        GLD_LDS16(A + (size_t)(m0 + 64 + srow) * K + k0 + scol,   As + 2048 + tid * 8);
        GLD_LDS16(Bw + (size_t)(n0 + srow) * K + k0 + scol,       Bs + tid * 8);
        GLD_LDS16(Bw + (size_t)(n0 + 64 + srow) * K + k0 + scol,  Bs + 2048 + tid * 8);
        __syncthreads();

        bf16x8 af[4], bg[4];
        #pragma unroll
        for (int i = 0; i < 4; ++i)
            af[i] = *(const bf16x8*)(As + (wm + i * 16 + lane15) * 32 + quad * 8);
        #pragma unroll
        for (int j = 0; j < 4; ++j)
            bg[j] = *(const bf16x8*)(Bs + (wn + j * 16 + lane15) * 32 + quad * 8);
        #pragma unroll
        for (int i = 0; i < 4; ++i)
            #pragma unroll
            for (int j = 0; j < 4; ++j)
                acc[i][j] = __builtin_amdgcn_mfma_f32_16x16x32_bf16(
                    af[i], bg[j], acc[i][j], 0, 0, 0);
        __syncthreads();
    }

    float* Es = (float*)(smem + wave * 4352);   // 16 rows x 68 floats
    const int r16 = lane >> 2;
    const int cg  = (lane & 3) * 16;
    #pragma unroll
    for (int i = 0; i < 4; ++i) {
        #pragma unroll
        for (int j = 0; j < 4; ++j)
            #pragma unroll
            for (int r = 0; r < 4; ++r)
                Es[(quad * 4 + r) * 68 + j * 16 + lane15] = acc[i][j][r];
        asm volatile("s_waitcnt lgkmcnt(0)" ::: "memory");

        int m = m0 + wm + i * 16 + r16;
        int nb = n0 + wn + cg;
        size_t gbase = (size_t)m * N + nb;
        float v[16];
        #pragma unroll
        for (int c = 0; c < 4; ++c) {
            f32x4 t = *(const f32x4*)&Es[r16 * 68 + cg + c * 4];
            v[c * 4 + 0] = t[0]; v[c * 4 + 1] = t[1];
            v[c * 4 + 2] = t[2]; v[c * 4 + 3] = t[3];
        }
        #pragma unroll
        for (int c = 0; c < 4; ++c) {
            float4 bb = *(const float4*)(bias + nb + c * 4);
            v[c * 4 + 0] += bb.x; v[c * 4 + 1] += bb.y;
            v[c * 4 + 2] += bb.z; v[c * 4 + 3] += bb.w;
        }
        if (gelu) {
            #pragma unroll
            for (int e = 0; e < 16; ++e) v[e] = gelu_fast(v[e]);
        }
        #pragma unroll
        for (int c = 0; c < 2; ++c) {
            uint4 o;
            o.x = f2bf(v[c * 8 + 0]) | ((unsigned)f2bf(v[c * 8 + 1]) << 16);
            o.y = f2bf(v[c * 8 + 2]) | ((unsigned)f2bf(v[c * 8 + 3]) << 16);
            o.z = f2bf(v[c * 8 + 4]) | ((unsigned)f2bf(v[c * 8 + 5]) << 16);
            o.w = f2bf(v[c * 8 + 6]) | ((unsigned)f2bf(v[c * 8 + 7]) << 16);
            *(uint4*)(Cb + gbase + c * 8) = o;
        }
        asm volatile("" ::: "memory");
    }
}

// --------------------------------------------------- MFMA gemm + fused LN --
// X = LN( A@Bw^T + bias + resid ) * lns + lnb   -> Xf (fp32) + Xb (bf16)
// N fixed = 256 (full row in one block). Tile M=64 x N=256; 4 waves side-by-
// side in N (wave w: cols w*64..w*64+64). Row stats: j-sums in regs, shfl_xor
// over the 16-lane groups, cross-wave reduce via LDS.
__global__ __launch_bounds__(256) void gemm_ln_kernel(
    const unsigned short* __restrict__ A, const unsigned short* __restrict__ Bw,
    const float* __restrict__ bias, const float* __restrict__ resid,
    const float* __restrict__ lns, const float* __restrict__ lnb,
    float* __restrict__ Xf, unsigned short* __restrict__ Xb, int K)
{
    __shared__ __align__(16) char smem[22528];
    unsigned short* As = (unsigned short*)smem;            // 64x32 = 4 KB
    unsigned short* Bs = (unsigned short*)(smem + 4096);   // 256x32 = 16 KB
    float* Ss = (float*)(smem + 20480);                    // [4][64] row sums
    float* Sq = Ss + 256;                                  // [4][64] row sqsums

    const int tid = threadIdx.x;
    const int lane = tid & 63, wave = tid >> 6;
    const int lane15 = lane & 15, quad = lane >> 4;
    const int wn = wave * 64;
    const int m0 = blockIdx.x * 64;

    f32x4 acc[4][4] = {};

    for (int k0 = 0; k0 < K; k0 += 32) {
        GLD_LDS16(A + (size_t)(m0 + (tid >> 2)) * K + k0 + (tid & 3) * 8, As + tid * 8);
        #pragma unroll
        for (int rr = 0; rr < 4; ++rr)
            GLD_LDS16(Bw + (size_t)(rr * 64 + (tid >> 2)) * K + k0 + (tid & 3) * 8,
                      Bs + rr * 2048 + tid * 8);
        __syncthreads();

        bf16x8 af[4], bg[4];
        #pragma unroll
        for (int i = 0; i < 4; ++i)
            af[i] = *(const bf16x8*)(As + (i * 16 + lane15) * 32 + quad * 8);
        #pragma unroll
        for (int j = 0; j < 4; ++j)
            bg[j] = *(const bf16x8*)(Bs + (wn + j * 16 + lane15) * 32 + quad * 8);
        #pragma unroll
        for (int i = 0; i < 4; ++i)
            #pragma unroll
            for (int j = 0; j < 4; ++j)
                acc[i][j] = __builtin_amdgcn_mfma_f32_16x16x32_bf16(
                    af[i], bg[j], acc[i][j], 0, 0, 0);
        __syncthreads();
    }

    // phase 1: + bias + resid (C-layout: col = wn+j*16+lane15, row = i*16+quad*4+r)
    float bj[4], scj[4], bbj[4];
    #pragma unroll
    for (int j = 0; j < 4; ++j) {
        int col = wn + j * 16 + lane15;
        bj[j] = bias[col]; scj[j] = lns[col]; bbj[j] = lnb[col];
    }
    #pragma unroll
    for (int i = 0; i < 4; ++i)
        #pragma unroll
        for (int r = 0; r < 4; ++r) {
            const float* rp = resid + (size_t)(m0 + i * 16 + quad * 4 + r) * DM + wn;
            #pragma unroll
            for (int j = 0; j < 4; ++j)
                acc[i][j][r] += bj[j] + rp[j * 16 + lane15];
        }

    // phase 2: per-row partial stats over this wave's 64 cols
    #pragma unroll
    for (int i = 0; i < 4; ++i)
        #pragma unroll
        for (int r = 0; r < 4; ++r) {
            float s = 0.f, q = 0.f;
            #pragma unroll
            for (int j = 0; j < 4; ++j) {
                float x = acc[i][j][r];
                s += x; q = fmaf(x, x, q);
            }
            #pragma unroll
            for (int off = 1; off < 16; off <<= 1) {
                s += __shfl_xor(s, off);
                q += __shfl_xor(q, off);
            }
            if (lane15 == 0) {
                int row = i * 16 + quad * 4 + r;
                Ss[wave * 64 + row] = s;
                Sq[wave * 64 + row] = q;
            }
        }
    __syncthreads();

    // phase 3: full-row stats + normalize (LDS reads are 16-lane broadcasts)
    #pragma unroll
    for (int i = 0; i < 4; ++i)
        #pragma unroll
        for (int r = 0; r < 4; ++r) {
            int row = i * 16 + quad * 4 + r;
            float s = Ss[row] + Ss[64 + row] + Ss[128 + row] + Ss[192 + row];
            float q = Sq[row] + Sq[64 + row] + Sq[128 + row] + Sq[192 + row];
            float mean = s * (1.0f / 256.0f);
            float var  = q * (1.0f / 256.0f) - mean * mean;
            float rinv = rsqrtf(var + 1e-5f);
            #pragma unroll
            for (int j = 0; j < 4; ++j)
                acc[i][j][r] = (acc[i][j][r] - mean) * rinv * scj[j] + bbj[j];
        }

    // phase 4: wave-private LDS transpose -> coalesced stores (Xf + Xb)
    float* Es = (float*)(smem + wave * 4352);   // 16 x 68 floats
    const int r16 = lane >> 2;
    const int cg  = (lane & 3) * 16;
    #pragma unroll
    for (int i = 0; i < 4; ++i) {
        #pragma unroll
        for (int j = 0; j < 4; ++j)
            #pragma unroll
            for (int r = 0; r < 4; ++r)
                Es[(quad * 4 + r) * 68 + j * 16 + lane15] = acc[i][j][r];
        asm volatile("s_waitcnt lgkmcnt(0)" ::: "memory");

        size_t gbase = (size_t)(m0 + i * 16 + r16) * DM + wn + cg;
        float v[16];
        #pragma unroll
        for (int c = 0; c < 4; ++c) {
            f32x4 t = *(const f32x4*)&Es[r16 * 68 + cg + c * 4];
            v[c * 4 + 0] = t[0]; v[c * 4 + 1] = t[1];
            v[c * 4 + 2] = t[2]; v[c * 4 + 3] = t[3];
        }
        #pragma unroll
        for (int c = 0; c < 4; ++c) {
            float4 o = { v[c * 4 + 0], v[c * 4 + 1], v[c * 4 + 2], v[c * 4 + 3] };
            *(float4*)(Xf + gbase + c * 4) = o;
        }
        #pragma unroll
        for (int c = 0; c < 2; ++c) {
            uint4 o;
            o.x = f2bf(v[c * 8 + 0]) | ((unsigned)f2bf(v[c * 8 + 1]) << 16);
            o.y = f2bf(v[c * 8 + 2]) | ((unsigned)f2bf(v[c * 8 + 3]) << 16);
            o.z = f2bf(v[c * 8 + 4]) | ((unsigned)f2bf(v[c * 8 + 5]) << 16);
            o.w = f2bf(v[c * 8 + 6]) | ((unsigned)f2bf(v[c * 8 + 7]) << 16);
            *(uint4*)(Xb + gbase + c * 8) = o;
        }
        asm volatile("" ::: "memory");
    }
}

// ------------------------------------------------------- MFMA attention ----
__global__ __launch_bounds__(64) void attn_mfma_kernel(
    const unsigned short* __restrict__ QKV, unsigned short* __restrict__ ATT)
{
    __shared__ __align__(16) char smem[22016];
    unsigned short* Qs = (unsigned short*)smem;           // [t][d] 64x32
    unsigned short* Ks = (unsigned short*)(smem + 4096);  // [t][d] 64x32
    unsigned short* VT = (unsigned short*)(smem + 8192);  // [d][t] 32 x pitch72
    unsigned short* Ps = (unsigned short*)(smem + 12800); // [q][k] 64 x pitch72
    float*          Po = (float*)(smem + 12800);          // [q][d] 64 x pitch36

    const int wg = blockIdx.x, h = blockIdx.y;
    const int base = wg * WIN;
    const int lane = threadIdx.x;
    const int l15 = lane & 15, quad = lane >> 4;
    const float scale = 0.17677669529663687f;   // 1/sqrt(32)

    const unsigned short* qkv = QKV + (size_t)base * 768;

    #pragma unroll
    for (int rr = 0; rr < 4; ++rr) {
        int chunk = rr * 64 + lane;
        int t = chunk >> 2, c4 = chunk & 3;
        GLD_LDS16(qkv + (size_t)t * 768 + h * 32 + c4 * 8,       Qs + (size_t)chunk * 8);
        GLD_LDS16(qkv + (size_t)t * 768 + 256 + h * 32 + c4 * 8, Ks + (size_t)chunk * 8);
    }
    u16x8 vv[4];
    #pragma unroll
    for (int cc = 0; cc < 4; ++cc)
        vv[cc] = *(const u16x8*)(qkv + (size_t)lane * 768 + 512 + h * 32 + cc * 8);
    #pragma unroll
    for (int cc = 0; cc < 4; ++cc)
        #pragma unroll
        for (int e = 0; e < 8; ++e)
            VT[(cc * 8 + e) * 72 + lane] = vv[cc][e];
    __syncthreads();

    const f32x4 zero4 = {0.f, 0.f, 0.f, 0.f};
    bf16x8 aq[4], bk[4];
    #pragma unroll
    for (int i = 0; i < 4; ++i)
        aq[i] = *(const bf16x8*)(Qs + (i * 16 + l15) * 32 + quad * 8);
    #pragma unroll
    for (int j = 0; j < 4; ++j)
        bk[j] = *(const bf16x8*)(Ks + (j * 16 + l15) * 32 + quad * 8);
    f32x4 S[4][4];
    #pragma unroll
    for (int i = 0; i < 4; ++i)
        #pragma unroll
        for (int j = 0; j < 4; ++j)
            S[i][j] = __builtin_amdgcn_mfma_f32_16x16x32_bf16(aq[i], bk[j], zero4, 0, 0, 0);

    float mx[4][4], sum[4][4];
    #pragma unroll
    for (int i = 0; i < 4; ++i)
        #pragma unroll
        for (int r = 0; r < 4; ++r) {
            float m0 = -1e30f;
            #pragma unroll
            for (int j = 0; j < 4; ++j) {
                S[i][j][r] *= scale;
                m0 = fmaxf(m0, S[i][j][r]);
            }
            mx[i][r] = m0;
        }
    #pragma unroll
    for (int off = 1; off < 16; off <<= 1)
        #pragma unroll
        for (int i = 0; i < 4; ++i)
            #pragma unroll
            for (int r = 0; r < 4; ++r)
                mx[i][r] = fmaxf(mx[i][r], __shfl_xor(mx[i][r], off));
    #pragma unroll
    for (int i = 0; i < 4; ++i)
        #pragma unroll
        for (int r = 0; r < 4; ++r) {
            float s0 = 0.f;
            #pragma unroll
            for (int j = 0; j < 4; ++j) {
                float e = __expf(S[i][j][r] - mx[i][r]);
                S[i][j][r] = e;
                s0 += e;
            }
            sum[i][r] = s0;
        }
    #pragma unroll
    for (int off = 1; off < 16; off <<= 1)
        #pragma unroll
        for (int i = 0; i < 4; ++i)
            #pragma unroll
            for (int r = 0; r < 4; ++r)
                sum[i][r] += __shfl_xor(sum[i][r], off);

    #pragma unroll
    for (int i = 0; i < 4; ++i)
        #pragma unroll
        for (int r = 0; r < 4; ++r) {
            float inv = 1.0f / sum[i][r];
            #pragma unroll
            for (int j = 0; j < 4; ++j)
                Ps[(i * 16 + quad * 4 + r) * 72 + j * 16 + l15] =
                    f2bf(S[i][j][r] * inv);
        }
    asm volatile("s_waitcnt lgkmcnt(0)" ::: "memory");

    bf16x8 ap0[4], ap1[4], bv0[2], bv1[2];
    #pragma unroll
    for (int i = 0; i < 4; ++i) {
        ap0[i] = *(const bf16x8*)(Ps + (i * 16 + l15) * 72 + quad * 8);
        ap1[i] = *(const bf16x8*)(Ps + (i * 16 + l15) * 72 + 32 + quad * 8);
    }
    #pragma unroll
    for (int jd = 0; jd < 2; ++jd) {
        bv0[jd] = *(const bf16x8*)(VT + (jd * 16 + l15) * 72 + quad * 8);
        bv1[jd] = *(const bf16x8*)(VT + (jd * 16 + l15) * 72 + 32 + quad * 8);
    }
    f32x4 O[4][2];
    #pragma unroll
    for (int i = 0; i < 4; ++i)
        #pragma unroll
        for (int jd = 0; jd < 2; ++jd) {
            f32x4 t = __builtin_amdgcn_mfma_f32_16x16x32_bf16(ap0[i], bv0[jd], zero4, 0, 0, 0);
            O[i][jd] = __builtin_amdgcn_mfma_f32_16x16x32_bf16(ap1[i], bv1[jd], t, 0, 0, 0);
        }
    asm volatile("s_waitcnt lgkmcnt(0)" ::: "memory");

    #pragma unroll
    for (int i = 0; i < 4; ++i)
        #pragma unroll
        for (int jd = 0; jd < 2; ++jd)
            #pragma unroll
            for (int r = 0; r < 4; ++r)
                Po[(i * 16 + quad * 4 + r) * 36 + jd * 16 + l15] = O[i][jd][r];
    asm volatile("s_waitcnt lgkmcnt(0)" ::: "memory");

    unsigned short* op = ATT + (size_t)(base + lane) * DM + h * 32;
    #pragma unroll
    for (int g = 0; g < 4; ++g) {
        f32x4 t0 = *(const f32x4*)(Po + lane * 36 + g * 8);
        f32x4 t1 = *(const f32x4*)(Po + lane * 36 + g * 8 + 4);
        uint4 w;
        w.x = f2bf(t0[0]) | ((unsigned)f2bf(t0[1]) << 16);
        w.y = f2bf(t0[2]) | ((unsigned)f2bf(t0[3]) << 16);
        w.z = f2bf(t1[0]) | ((unsigned)f2bf(t1[1]) << 16);
        w.w = f2bf(t1[2]) | ((unsigned)f2bf(t1[3]) << 16);
        *(uint4*)(op + g * 8) = w;
    }
}

// ---------------------------------------------- final LN + transpose out ---
__global__ __launch_bounds__(256) void out_ln_kernel(
    const float* __restrict__ Xf, const float* __restrict__ sc,
    const float* __restrict__ bi, float* __restrict__ out)
{
    __shared__ float mean_s[64], rinv_s[64];
    __shared__ float tile[64][65];
    int b = blockIdx.y, l0 = blockIdx.x * 64;
    int tid = threadIdx.x, wave = tid >> 6, lane = tid & 63;
    int c = lane * 4;
    #pragma unroll
    for (int it = 0; it < 16; ++it) {
        int tl = wave * 16 + it;
        float4 v = *(const float4*)(Xf + ((size_t)(b * LSEQ + l0 + tl)) * DM + c);
        float sm = v.x + v.y + v.z + v.w;
        float sq = v.x * v.x + v.y * v.y + v.z * v.z + v.w * v.w;
        #pragma unroll
        for (int off = 32; off > 0; off >>= 1) {
            sm += __shfl_down(sm, off);
            sq += __shfl_down(sq, off);
        }
        if (lane == 0) {
            float mean = sm * (1.0f / 256.0f);
            float var  = sq * (1.0f / 256.0f) - mean * mean;
            mean_s[tl] = mean;
            rinv_s[tl] = rsqrtf(var + 1e-5f);
        }
    }
    __syncthreads();
    #pragma unroll
    for (int ct = 0; ct < 4; ++ct) {
        int c0 = ct * 64;
        int cin = tid & 63, lin = tid >> 6;
        #pragma unroll
        for (int it = 0; it < 16; ++it) {
            int l = lin + it * 4;
            float v = Xf[((size_t)(b * LSEQ + l0 + l)) * DM + c0 + cin];
            tile[l][cin] = (v - mean_s[l]) * rinv_s[l] * sc[c0 + cin] + bi[c0 + cin];
        }
        __syncthreads();
        int lout = tid & 63, crow = tid >> 6;
        #pragma unroll
        for (int it = 0; it < 16; ++it) {
            int cc = crow + it * 4;
            out[((size_t)(b * DM + c0 + cc)) * LSEQ + l0 + lout] = tile[lout][cc];
        }
        __syncthreads();
    }
}

// ----------------------------------------------------------------- driver --
extern "C" void kernel_launch(void* const* d_in, const int* in_sizes, int n_in,
                              void* d_out, int out_size, void* d_ws, size_t ws_size,
                              hipStream_t stream)
{
    const float* F   = (const float*)d_in[0];
    const float* Wi  = (const float*)d_in[1];
    const float* Bi  = (const float*)d_in[2];
    const float* Wo  = (const float*)d_in[3];
    const float* Bo  = (const float*)d_in[4];
    const float* W1  = (const float*)d_in[5];
    const float* B1  = (const float*)d_in[6];
    const float* W2  = (const float*)d_in[7];
    const float* B2  = (const float*)d_in[8];
    const float* L1s = (const float*)d_in[9];
    const float* L1b = (const float*)d_in[10];
    const float* L2s = (const float*)d_in[11];
    const float* L2b = (const float*)d_in[12];
    const float* Fs  = (const float*)d_in[13];
    const float* Fb  = (const float*)d_in[14];

    char* w = (char*)d_ws;
    float*          Xf   = (float*)w;                              // 33.5 MB
    unsigned short* QKVb = (unsigned short*)(w + 33554432);        // 50 MB
    unsigned short* Hb   = (unsigned short*)(w + 83886080);        // 67 MB
    unsigned short* Xb   = (unsigned short*)(w + 150994944);       // 16.8 MB
    unsigned short* ATTb = (unsigned short*)(w + 167772160);       // 16.8 MB
    unsigned short* WB   = (unsigned short*)(w + 184549376);       // 4.7 MB
    float*          PE   = (float*)(w + 189267968);                // 1 MB
    unsigned short* Wib  = WB;
    unsigned short* Wob  = WB + 589824;
    unsigned short* W1b  = WB + 786432;
    unsigned short* W2b  = WB + 1572864;

    cvt_kernel<<<589824 / 1024, 256, 0, stream>>>(Wi, Wib, 589824);
    cvt_kernel<<<196608 / 1024, 256, 0, stream>>>(Wo, Wob, 196608);
    cvt_kernel<<<786432 / 1024, 256, 0, stream>>>(W1, W1b, 786432);
    cvt_kernel<<<786432 / 1024, 256, 0, stream>>>(W2, W2b, 786432);
    pe_kernel<<<LSEQ, 256, 0, stream>>>(PE);
    embed_kernel<<<dim3(DM / 64, LSEQ / 64, BSZ), 256, 0, stream>>>(F, PE, Xf, Xb);

    for (int i = 0; i < 3; ++i) {
        // QKV = X @ Wi^T + bi -> QKVb (bf16)
        gemm_mfma_kernel<<<dim3(MTOK / 128, 768 / 128), 256, 0, stream>>>(
            Xb, Wib + (size_t)i * 196608, Bi + i * 768, QKVb, MTOK, 768, DM, 0);
        // windowed MHA -> ATTb (bf16)
        attn_mfma_kernel<<<dim3(BSZ * (LSEQ / WIN), NHEAD), 64, 0, stream>>>(QKVb, ATTb);
        // X = LN1( ATT @ Wo^T + bo + X )  (fused) -> Xf + Xb
        gemm_ln_kernel<<<MTOK / 64, 256, 0, stream>>>(
            ATTb, Wob + (size_t)i * 65536, Bo + i * DM, Xf,
            L1s + i * DM, L1b + i * DM, Xf, Xb, DM);
        // H = GELU(X @ W1^T + b1) -> Hb (bf16)
        gemm_mfma_kernel<<<dim3(MTOK / 128, DFF / 128), 256, 0, stream>>>(
            Xb, W1b + (size_t)i * 262144, B1 + i * DFF, Hb, MTOK, DFF, DM, 1);
        // X = LN2( H @ W2^T + b2 + X )  (fused) -> Xf + Xb
        gemm_ln_kernel<<<MTOK / 64, 256, 0, stream>>>(
            Hb, W2b + (size_t)i * 262144, B2 + i * DM, Xf,
            L2s + i * DM, L2b + i * DM, Xf, Xb, DFF);
    }

    out_ln_kernel<<<dim3(LSEQ / 64, BSZ), 256, 0, stream>>>(
        Xf, Fs, Fb, (float*)d_out);
}

// Round 8
// 648.636 us; speedup vs baseline: 5.4741x; 1.0775x over previous
//
#include <hip/hip_runtime.h>
#include <hip/hip_bf16.h>

// EfficientTransformerEncoder: B=32, D=256, L=1024, NH=8, DH=32, WIN=64, DFF=1024, NL=3.
// Inputs fp32. All bf16 tensors use k-chunk-major layout T[k/8][row][8] so MFMA
// fragments are direct coalesced global_load_dwordx4 (register-direct GEMM:
// no LDS staging, no barriers in the K-loop). fp32 accumulate; out fp32.
#define BSZ 32
#define DM 256
#define LSEQ 1024
#define MTOK (BSZ * LSEQ)   // 32768 tokens
#define NHEAD 8
#define DHEAD 32
#define WIN 64
#define DFF 1024
#define M8 ((size_t)MTOK * 8)   // chunk stride (shorts) for M-row activations

typedef short bf16x8 __attribute__((ext_vector_type(8)));
typedef float f32x4 __attribute__((ext_vector_type(4)));
typedef unsigned short u16x8 __attribute__((ext_vector_type(8)));

union BF { __hip_bfloat16 h; unsigned short u; };
__device__ __forceinline__ unsigned short f2bf(float f) { BF b; b.h = __float2bfloat16(f); return b.u; }
__device__ __forceinline__ float bf2f(unsigned short u) { return __uint_as_float((unsigned)u << 16); }

#define GLD_LDS16(gp, lp) __builtin_amdgcn_global_load_lds( \
    (const __attribute__((address_space(1))) void*)(gp),    \
    (__attribute__((address_space(3))) void*)(lp), 16, 0, 0)

// tanh-form GELU (validated round 7)
__device__ __forceinline__ float gelu_fast(float x) {
    float t = x * (0.7978845608f + 0.0356774081f * x * x);
    return x / (1.0f + __expf(-2.0f * t));
}

// ------------------------------------------------------------- weight cvt --
// fp32 [nl][N][K] row-major -> bf16 [nl][K/8][N][8] (k-chunk-major per layer)
__global__ __launch_bounds__(256) void cvt_kernel(
    const float* __restrict__ s, unsigned short* __restrict__ d,
    int N, int K, int nl)
{
    int K8 = K >> 3;
    int per = N * K8;
    int c = blockIdx.x * 256 + threadIdx.x;
    if (c >= per * nl) return;
    int layer = c / per, rem = c - layer * per;
    int n = rem / K8, kc = rem - n * K8;
    const float* sp = s + (size_t)layer * N * K + (size_t)n * K + kc * 8;
    float4 v0 = *(const float4*)sp, v1 = *(const float4*)(sp + 4);
    uint4 o;
    o.x = f2bf(v0.x) | ((unsigned)f2bf(v0.y) << 16);
    o.y = f2bf(v0.z) | ((unsigned)f2bf(v0.w) << 16);
    o.z = f2bf(v1.x) | ((unsigned)f2bf(v1.y) << 16);
    o.w = f2bf(v1.z) | ((unsigned)f2bf(v1.w) << 16);
    *(uint4*)(d + (size_t)layer * N * K + (size_t)kc * N * 8 + (size_t)n * 8) = o;
}

// -------------------------------------------------------------- PE table ---
__global__ __launch_bounds__(256) void pe_kernel(float* __restrict__ PE)
{
    int l = blockIdx.x, c = threadIdx.x;
    int i2 = c & ~1;
    float div = expf(-9.210340371976184f * (float)i2 / 256.0f);  // -ln(10000)
    float ang = (float)l * div;
    PE[l * DM + c] = (c & 1) ? cosf(ang) : sinf(ang);
}

// ---------------------------------------------------------------- embed ----
// Xf row-major fp32; Xb k-chunk-major bf16.
__global__ __launch_bounds__(256) void embed_kernel(
    const float* __restrict__ F, const float* __restrict__ PE,
    float* __restrict__ Xf, unsigned short* __restrict__ Xb)
{
    __shared__ float tile[64][65];
    int b = blockIdx.z, l0 = blockIdx.y * 64, c0 = blockIdx.x * 64;
    int tid = threadIdx.x;
    int li = tid & 63, c4 = tid >> 6;
    #pragma unroll
    for (int it = 0; it < 16; ++it) {
        int c = c4 + it * 4;
        tile[c][li] = F[((size_t)(b * DM + c0 + c)) * LSEQ + l0 + li];
    }
    __syncthreads();
    // Xf: row-major coalesced
    int ci = tid & 63, l4 = tid >> 6;
    #pragma unroll
    for (int it = 0; it < 16; ++it) {
        int l = l4 + it * 4;
        float x = tile[ci][l] + PE[(l0 + l) * DM + c0 + ci];
        Xf[((size_t)b * LSEQ + l0 + l) * DM + c0 + ci] = x;
    }
    // Xb: k-chunk-major, 16B per store, contiguous across 32-lane groups
    int ch = tid >> 5;          // chunk within this c0-range (0..7)
    int lx = tid & 31;
    #pragma unroll
    for (int rd = 0; rd < 2; ++rd) {
        int l = lx + rd * 32;
        unsigned short vs[8];
        #pragma unroll
        for (int e = 0; e < 8; ++e) {
            int c = ch * 8 + e;
            vs[e] = f2bf(tile[c][l] + PE[(l0 + l) * DM + c0 + c]);
        }
        uint4 o;
        o.x = vs[0] | ((unsigned)vs[1] << 16);
        o.y = vs[2] | ((unsigned)vs[3] << 16);
        o.z = vs[4] | ((unsigned)vs[5] << 16);
        o.w = vs[6] | ((unsigned)vs[7] << 16);
        *(uint4*)(Xb + ((size_t)((c0 >> 3) + ch)) * M8 +
                  (size_t)(b * LSEQ + l0 + l) * 8) = o;
    }
}

// ----------------------------------------------- register-direct MFMA gemm --
// Cb[n-chunk][m][8] = epi( A[kc][m][8] @ Bw[kc][n][8] + bias[n] ).
// Tile 128x128, 4 waves (2x2), 2-stage pipelined K-loop, NO LDS staging.
__global__ __launch_bounds__(256) void gemm_mfma_kernel(
    const unsigned short* __restrict__ A, const unsigned short* __restrict__ Bw,
    const float* __restrict__ bias, unsigned short* __restrict__ Cb,
    int M, int N, int K, int gelu)
{
    __shared__ __align__(16) char smem[17408];      // epilogue transpose only
    const int tid = threadIdx.x;
    const int lane = tid & 63, wave = tid >> 6;
    const int l15 = lane & 15, quad = lane >> 4;
    const int wm = (wave & 1) * 64, wn = (wave >> 1) * 64;
    const int m0 = blockIdx.x * 128, n0 = blockIdx.y * 128;
    const size_t Ma8 = (size_t)M * 8, Nb8 = (size_t)N * 8;
    const size_t astep = 4 * Ma8, bstep = 4 * Nb8;

    const unsigned short* ap[4];
    const unsigned short* bp[4];
    #pragma unroll
    for (int i = 0; i < 4; ++i)
        ap[i] = A + quad * Ma8 + (size_t)(m0 + wm + i * 16 + l15) * 8;
    #pragma unroll
    for (int j = 0; j < 4; ++j)
        bp[j] = Bw + quad * Nb8 + (size_t)(n0 + wn + j * 16 + l15) * 8;

    f32x4 acc[4][4] = {};
    bf16x8 aA[4], bA[4], aB[4], bB[4];
    #pragma unroll
    for (int i = 0; i < 4; ++i) aA[i] = *(const bf16x8*)(ap[i]);
    #pragma unroll
    for (int j = 0; j < 4; ++j) bA[j] = *(const bf16x8*)(bp[j]);

    const int iters = K >> 5;   // 8 or 32 (even)
    for (int t = 0; t < iters; t += 2) {
        size_t o1 = (size_t)(t + 1);
        #pragma unroll
        for (int i = 0; i < 4; ++i) aB[i] = *(const bf16x8*)(ap[i] + o1 * astep);
        #pragma unroll
        for (int j = 0; j < 4; ++j) bB[j] = *(const bf16x8*)(bp[j] + o1 * bstep);
        #pragma unroll
        for (int i = 0; i < 4; ++i)
            #pragma unroll
            for (int j = 0; j < 4; ++j)
                acc[i][j] = __builtin_amdgcn_mfma_f32_16x16x32_bf16(
                    aA[i], bA[j], acc[i][j], 0, 0, 0);
        size_t o2 = (size_t)((t + 2 < iters) ? t + 2 : iters - 1);
        #pragma unroll
        for (int i = 0; i < 4; ++i) aA[i] = *(const bf16x8*)(ap[i] + o2 * astep);
        #pragma unroll
        for (int j = 0; j < 4; ++j) bA[j] = *(const bf16x8*)(bp[j] + o2 * bstep);
        #pragma unroll
        for (int i = 0; i < 4; ++i)
            #pragma unroll
            for (int j = 0; j < 4; ++j)
                acc[i][j] = __builtin_amdgcn_mfma_f32_16x16x32_bf16(
                    aB[i], bB[j], acc[i][j], 0, 0, 0);
    }

    // epilogue: wave-private LDS transpose -> bias(+gelu) -> k-chunk bf16 stores
    float* Es = (float*)(smem + wave * 4352);   // 16 x 68 floats
    const int r16 = lane >> 2;
    const int cg  = (lane & 3) * 16;
    #pragma unroll
    for (int i = 0; i < 4; ++i) {
        #pragma unroll
        for (int j = 0; j < 4; ++j)
            #pragma unroll
            for (int r = 0; r < 4; ++r)
                Es[(quad * 4 + r) * 68 + j * 16 + l15] = acc[i][j][r];
        asm volatile("s_waitcnt lgkmcnt(0)" ::: "memory");

        int m = m0 + wm + i * 16 + r16;
        int nb = n0 + wn + cg;
        float v[16];
        #pragma unroll
        for (int c = 0; c < 4; ++c) {
            f32x4 t = *(const f32x4*)&Es[r16 * 68 + cg + c * 4];
            v[c * 4 + 0] = t[0]; v[c * 4 + 1] = t[1];
            v[c * 4 + 2] = t[2]; v[c * 4 + 3] = t[3];
        }
        #pragma unroll
        for (int c = 0; c < 4; ++c) {
            float4 bb = *(const float4*)(bias + nb + c * 4);
            v[c * 4 + 0] += bb.x; v[c * 4 + 1] += bb.y;
            v[c * 4 + 2] += bb.z; v[c * 4 + 3] += bb.w;
        }
        if (gelu) {
            #pragma unroll
            for (int e = 0; e < 16; ++e) v[e] = gelu_fast(v[e]);
        }
        size_t gb = ((size_t)(nb >> 3)) * Ma8 + (size_t)m * 8;
        #pragma unroll
        for (int c = 0; c < 2; ++c) {
            uint4 o;
            o.x = f2bf(v[c * 8 + 0]) | ((unsigned)f2bf(v[c * 8 + 1]) << 16);
            o.y = f2bf(v[c * 8 + 2]) | ((unsigned)f2bf(v[c * 8 + 3]) << 16);
            o.z = f2bf(v[c * 8 + 4]) | ((unsigned)f2bf(v[c * 8 + 5]) << 16);
            o.w = f2bf(v[c * 8 + 6]) | ((unsigned)f2bf(v[c * 8 + 7]) << 16);
            *(uint4*)(Cb + gb + (size_t)c * Ma8) = o;
        }
        asm volatile("" ::: "memory");
    }
}

// --------------------------------- register-direct MFMA gemm + fused LN ----
// X = LN( A@Bw^T + bias + resid ) -> Xf (row-major fp32) + Xb (k-chunk bf16).
// N fixed 256; tile M=64 x N=256, 4 waves side-by-side in N.
__global__ __launch_bounds__(256) void gemm_ln_kernel(
    const unsigned short* __restrict__ A, const unsigned short* __restrict__ Bw,
    const float* __restrict__ bias, const float* __restrict__ resid,
    const float* __restrict__ lns, const float* __restrict__ lnb,
    float* __restrict__ Xf, unsigned short* __restrict__ Xb, int K)
{
    __shared__ __align__(16) char smem[17408];
    __shared__ float Ss[256], Sq[256];
    const int tid = threadIdx.x;
    const int lane = tid & 63, wave = tid >> 6;
    const int l15 = lane & 15, quad = lane >> 4;
    const int wn = wave * 64;
    const int m0 = blockIdx.x * 64;
    const size_t Nb8 = (size_t)DM * 8;
    const size_t astep = 4 * M8, bstep = 4 * Nb8;

    const unsigned short* ap[4];
    const unsigned short* bp[4];
    #pragma unroll
    for (int i = 0; i < 4; ++i)
        ap[i] = A + quad * M8 + (size_t)(m0 + i * 16 + l15) * 8;
    #pragma unroll
    for (int j = 0; j < 4; ++j)
        bp[j] = Bw + quad * Nb8 + (size_t)(wn + j * 16 + l15) * 8;

    f32x4 acc[4][4] = {};
    bf16x8 aA[4], bA[4], aB[4], bB[4];
    #pragma unroll
    for (int i = 0; i < 4; ++i) aA[i] = *(const bf16x8*)(ap[i]);
    #pragma unroll
    for (int j = 0; j < 4; ++j) bA[j] = *(const bf16x8*)(bp[j]);

    const int iters = K >> 5;
    for (int t = 0; t < iters; t += 2) {
        size_t o1 = (size_t)(t + 1);
        #pragma unroll
        for (int i = 0; i < 4; ++i) aB[i] = *(const bf16x8*)(ap[i] + o1 * astep);
        #pragma unroll
        for (int j = 0; j < 4; ++j) bB[j] = *(const bf16x8*)(bp[j] + o1 * bstep);
        #pragma unroll
        for (int i = 0; i < 4; ++i)
            #pragma unroll
            for (int j = 0; j < 4; ++j)
                acc[i][j] = __builtin_amdgcn_mfma_f32_16x16x32_bf16(
                    aA[i], bA[j], acc[i][j], 0, 0, 0);
        size_t o2 = (size_t)((t + 2 < iters) ? t + 2 : iters - 1);
        #pragma unroll
        for (int i = 0; i < 4; ++i) aA[i] = *(const bf16x8*)(ap[i] + o2 * astep);
        #pragma unroll
        for (int j = 0; j < 4; ++j) bA[j] = *(const bf16x8*)(bp[j] + o2 * bstep);
        #pragma unroll
        for (int i = 0; i < 4; ++i)
            #pragma unroll
            for (int j = 0; j < 4; ++j)
                acc[i][j] = __builtin_amdgcn_mfma_f32_16x16x32_bf16(
                    aB[i], bB[j], acc[i][j], 0, 0, 0);
    }

    // + bias + resid
    float bj[4], scj[4], bbj[4];
    #pragma unroll
    for (int j = 0; j < 4; ++j) {
        int col = wn + j * 16 + l15;
        bj[j] = bias[col]; scj[j] = lns[col]; bbj[j] = lnb[col];
    }
    #pragma unroll
    for (int i = 0; i < 4; ++i)
        #pragma unroll
        for (int r = 0; r < 4; ++r) {
            const float* rp = resid + (size_t)(m0 + i * 16 + quad * 4 + r) * DM + wn;
            #pragma unroll
            for (int j = 0; j < 4; ++j)
                acc[i][j][r] += bj[j] + rp[j * 16 + l15];
        }

    // row stats (partial per wave, then cross-wave via LDS)
    #pragma unroll
    for (int i = 0; i < 4; ++i)
        #pragma unroll
        for (int r = 0; r < 4; ++r) {
            float s = 0.f, q = 0.f;
            #pragma unroll
            for (int j = 0; j < 4; ++j) {
                float x = acc[i][j][r];
                s += x; q = fmaf(x, x, q);
            }
            #pragma unroll
            for (int off = 1; off < 16; off <<= 1) {
                s += __shfl_xor(s, off);
                q += __shfl_xor(q, off);
            }
            if (l15 == 0) {
                int row = i * 16 + quad * 4 + r;
                Ss[wave * 64 + row] = s;
                Sq[wave * 64 + row] = q;
            }
        }
    __syncthreads();
    #pragma unroll
    for (int i = 0; i < 4; ++i)
        #pragma unroll
        for (int r = 0; r < 4; ++r) {
            int row = i * 16 + quad * 4 + r;
            float s = Ss[row] + Ss[64 + row] + Ss[128 + row] + Ss[192 + row];
            float q = Sq[row] + Sq[64 + row] + Sq[128 + row] + Sq[192 + row];
            float mean = s * (1.0f / 256.0f);
            float var  = q * (1.0f / 256.0f) - mean * mean;
            float rinv = rsqrtf(var + 1e-5f);
            #pragma unroll
            for (int j = 0; j < 4; ++j)
                acc[i][j][r] = (acc[i][j][r] - mean) * rinv * scj[j] + bbj[j];
        }

    // epilogue: transpose -> Xf (row-major) + Xb (k-chunk)
    float* Es = (float*)(smem + wave * 4352);
    const int r16 = lane >> 2;
    const int cg  = (lane & 3) * 16;
    #pragma unroll
    for (int i = 0; i < 4; ++i) {
        #pragma unroll
        for (int j = 0; j < 4; ++j)
            #pragma unroll
            for (int r = 0; r < 4; ++r)
                Es[(quad * 4 + r) * 68 + j * 16 + l15] = acc[i][j][r];
        asm volatile("s_waitcnt lgkmcnt(0)" ::: "memory");

        int m = m0 + i * 16 + r16;
        float v[16];
        #pragma unroll
        for (int c = 0; c < 4; ++c) {
            f32x4 t = *(const f32x4*)&Es[r16 * 68 + cg + c * 4];
            v[c * 4 + 0] = t[0]; v[c * 4 + 1] = t[1];
            v[c * 4 + 2] = t[2]; v[c * 4 + 3] = t[3];
        }
        size_t gf = (size_t)m * DM + wn + cg;
        #pragma unroll
        for (int c = 0; c < 4; ++c) {
            float4 o = { v[c * 4 + 0], v[c * 4 + 1], v[c * 4 + 2], v[c * 4 + 3] };
            *(float4*)(Xf + gf + c * 4) = o;
        }
        size_t gb = ((size_t)((wn + cg) >> 3)) * M8 + (size_t)m * 8;
        #pragma unroll
        for (int c = 0; c < 2; ++c) {
            uint4 o;
            o.x = f2bf(v[c * 8 + 0]) | ((unsigned)f2bf(v[c * 8 + 1]) << 16);
            o.y = f2bf(v[c * 8 + 2]) | ((unsigned)f2bf(v[c * 8 + 3]) << 16);
            o.z = f2bf(v[c * 8 + 4]) | ((unsigned)f2bf(v[c * 8 + 5]) << 16);
            o.w = f2bf(v[c * 8 + 6]) | ((unsigned)f2bf(v[c * 8 + 7]) << 16);
            *(uint4*)(Xb + gb + (size_t)c * M8) = o;
        }
        asm volatile("" ::: "memory");
    }
}

// ------------------------------------------------------- MFMA attention ----
// QKV/ATT in k-chunk-major layout. One wave per (window, head).
__global__ __launch_bounds__(64) void attn_mfma_kernel(
    const unsigned short* __restrict__ QKV, unsigned short* __restrict__ ATT)
{
    __shared__ __align__(16) char smem[22016];
    unsigned short* Qs = (unsigned short*)smem;           // [dc][t][8] 4x64x8
    unsigned short* Ks = (unsigned short*)(smem + 4096);  // [dc][t][8]
    unsigned short* VT = (unsigned short*)(smem + 8192);  // [d][t] 32 x pitch72
    unsigned short* Ps = (unsigned short*)(smem + 12800); // [q][k] 64 x pitch72
    float*          Po = (float*)(smem + 12800);          // [q][d] 64 x pitch36

    const int wg = blockIdx.x, h = blockIdx.y;
    const int base = wg * WIN;
    const int lane = threadIdx.x;
    const int l15 = lane & 15, quad = lane >> 4;
    const float scale = 0.17677669529663687f;   // 1/sqrt(32)

    // stage Q,K: chunk-major source -> contiguous 1KB per DMA instruction
    #pragma unroll
    for (int dc = 0; dc < 4; ++dc) {
        GLD_LDS16(QKV + ((size_t)(h * 4 + dc)) * M8 + (size_t)(base + lane) * 8,
                  Qs + dc * 512 + (size_t)lane * 8);
        GLD_LDS16(QKV + ((size_t)(32 + h * 4 + dc)) * M8 + (size_t)(base + lane) * 8,
                  Ks + dc * 512 + (size_t)lane * 8);
    }
    u16x8 vv[4];
    #pragma unroll
    for (int cc = 0; cc < 4; ++cc)
        vv[cc] = *(const u16x8*)(QKV + ((size_t)(64 + h * 4 + cc)) * M8 +
                                 (size_t)(base + lane) * 8);
    #pragma unroll
    for (int cc = 0; cc < 4; ++cc)
        #pragma unroll
        for (int e = 0; e < 8; ++e)
            VT[(cc * 8 + e) * 72 + lane] = vv[cc][e];
    __syncthreads();   // drains vmcnt (DMA) + lgkm (VT writes)

    const f32x4 zero4 = {0.f, 0.f, 0.f, 0.f};
    bf16x8 aq[4], bk[4];
    #pragma unroll
    for (int i = 0; i < 4; ++i)
        aq[i] = *(const bf16x8*)(Qs + quad * 512 + (i * 16 + l15) * 8);
    #pragma unroll
    for (int j = 0; j < 4; ++j)
        bk[j] = *(const bf16x8*)(Ks + quad * 512 + (j * 16 + l15) * 8);
    f32x4 S[4][4];
    #pragma unroll
    for (int i = 0; i < 4; ++i)
        #pragma unroll
        for (int j = 0; j < 4; ++j)
            S[i][j] = __builtin_amdgcn_mfma_f32_16x16x32_bf16(aq[i], bk[j], zero4, 0, 0, 0);

    float mx[4][4], sum[4][4];
    #pragma unroll
    for (int i = 0; i < 4; ++i)
        #pragma unroll
        for (int r = 0; r < 4; ++r) {
            float m0 = -1e30f;
            #pragma unroll
            for (int j = 0; j < 4; ++j) {
                S[i][j][r] *= scale;
                m0 = fmaxf(m0, S[i][j][r]);
            }
            mx[i][r] = m0;
        }
    #pragma unroll
    for (int off = 1; off < 16; off <<= 1)
        #pragma unroll
        for (int i = 0; i < 4; ++i)
            #pragma unroll
            for (int r = 0; r < 4; ++r)
                mx[i][r] = fmaxf(mx[i][r], __shfl_xor(mx[i][r], off));
    #pragma unroll
    for (int i = 0; i < 4; ++i)
        #pragma unroll
        for (int r = 0; r < 4; ++r) {
            float s0 = 0.f;
            #pragma unroll
            for (int j = 0; j < 4; ++j) {
                float e = __expf(S[i][j][r] - mx[i][r]);
                S[i][j][r] = e;
                s0 += e;
            }
            sum[i][r] = s0;
        }
    #pragma unroll
    for (int off = 1; off < 16; off <<= 1)
        #pragma unroll
        for (int i = 0; i < 4; ++i)
            #pragma unroll
            for (int r = 0; r < 4; ++r)
                sum[i][r] += __shfl_xor(sum[i][r], off);

    #pragma unroll
    for (int i = 0; i < 4; ++i)
        #pragma unroll
        for (int r = 0; r < 4; ++r) {
            float inv = 1.0f / sum[i][r];
            #pragma unroll
            for (int j = 0; j < 4; ++j)
                Ps[(i * 16 + quad * 4 + r) * 72 + j * 16 + l15] =
                    f2bf(S[i][j][r] * inv);
        }
    asm volatile("s_waitcnt lgkmcnt(0)" ::: "memory");

    bf16x8 ap0[4], ap1[4], bv0[2], bv1[2];
    #pragma unroll
    for (int i = 0; i < 4; ++i) {
        ap0[i] = *(const bf16x8*)(Ps + (i * 16 + l15) * 72 + quad * 8);
        ap1[i] = *(const bf16x8*)(Ps + (i * 16 + l15) * 72 + 32 + quad * 8);
    }
    #pragma unroll
    for (int jd = 0; jd < 2; ++jd) {
        bv0[jd] = *(const bf16x8*)(VT + (jd * 16 + l15) * 72 + quad * 8);
        bv1[jd] = *(const bf16x8*)(VT + (jd * 16 + l15) * 72 + 32 + quad * 8);
    }
    f32x4 O[4][2];
    #pragma unroll
    for (int i = 0; i < 4; ++i)
        #pragma unroll
        for (int jd = 0; jd < 2; ++jd) {
            f32x4 t = __builtin_amdgcn_mfma_f32_16x16x32_bf16(ap0[i], bv0[jd], zero4, 0, 0, 0);
            O[i][jd] = __builtin_amdgcn_mfma_f32_16x16x32_bf16(ap1[i], bv1[jd], t, 0, 0, 0);
        }
    asm volatile("s_waitcnt lgkmcnt(0)" ::: "memory");

    #pragma unroll
    for (int i = 0; i < 4; ++i)
        #pragma unroll
        for (int jd = 0; jd < 2; ++jd)
            #pragma unroll
            for (int r = 0; r < 4; ++r)
                Po[(i * 16 + quad * 4 + r) * 36 + jd * 16 + l15] = O[i][jd][r];
    asm volatile("s_waitcnt lgkmcnt(0)" ::: "memory");

    // ATT out: k-chunk-major, contiguous 1KB per chunk store
    #pragma unroll
    for (int g = 0; g < 4; ++g) {
        f32x4 t0 = *(const f32x4*)(Po + lane * 36 + g * 8);
        f32x4 t1 = *(const f32x4*)(Po + lane * 36 + g * 8 + 4);
        uint4 w;
        w.x = f2bf(t0[0]) | ((unsigned)f2bf(t0[1]) << 16);
        w.y = f2bf(t0[2]) | ((unsigned)f2bf(t0[3]) << 16);
        w.z = f2bf(t1[0]) | ((unsigned)f2bf(t1[1]) << 16);
        w.w = f2bf(t1[2]) | ((unsigned)f2bf(t1[3]) << 16);
        *(uint4*)(ATT + ((size_t)(h * 4 + g)) * M8 + (size_t)(base + lane) * 8) = w;
    }
}

// ---------------------------------------------- final LN + transpose out ---
// single pass: tile 64 tokens x 256 ch in LDS (pitch 257), stats inline.
__global__ __launch_bounds__(256) void out_ln_kernel(
    const float* __restrict__ Xf, const float* __restrict__ sc,
    const float* __restrict__ bi, float* __restrict__ out)
{
    __shared__ float tile[64][257];
    __shared__ float mean_s[64], rinv_s[64];
    int b = blockIdx.y, l0 = blockIdx.x * 64;
    int tid = threadIdx.x, wave = tid >> 6, lane = tid & 63;
    int c = lane * 4;
    #pragma unroll
    for (int it = 0; it < 16; ++it) {
        int tl = wave * 16 + it;
        float4 v = *(const float4*)(Xf + ((size_t)(b * LSEQ + l0 + tl)) * DM + c);
        *(float4*)&tile[tl][c] = v;
        float sm = v.x + v.y + v.z + v.w;
        float sq = v.x * v.x + v.y * v.y + v.z * v.z + v.w * v.w;
        #pragma unroll
        for (int off = 32; off > 0; off >>= 1) {
            sm += __shfl_down(sm, off);
            sq += __shfl_down(sq, off);
        }
        if (lane == 0) {
            float mean = sm * (1.0f / 256.0f);
            float var  = sq * (1.0f / 256.0f) - mean * mean;
            mean_s[tl] = mean;
            rinv_s[tl] = rsqrtf(var + 1e-5f);
        }
    }
    __syncthreads();
    int lout = tid & 63, crow = tid >> 6;
    #pragma unroll
    for (int ct = 0; ct < 4; ++ct) {
        int c0 = ct * 64;
        #pragma unroll
        for (int it = 0; it < 16; ++it) {
            int cc = c0 + crow + it * 4;
            float v = tile[lout][cc];
            out[((size_t)(b * DM + cc)) * LSEQ + l0 + lout] =
                (v - mean_s[lout]) * rinv_s[lout] * sc[cc] + bi[cc];
        }
    }
}

// ----------------------------------------------------------------- driver --
extern "C" void kernel_launch(void* const* d_in, const int* in_sizes, int n_in,
                              void* d_out, int out_size, void* d_ws, size_t ws_size,
                              hipStream_t stream)
{
    const float* F   = (const float*)d_in[0];
    const float* Wi  = (const float*)d_in[1];
    const float* Bi  = (const float*)d_in[2];
    const float* Wo  = (const float*)d_in[3];
    const float* Bo  = (const float*)d_in[4];
    const float* W1  = (const float*)d_in[5];
    const float* B1  = (const float*)d_in[6];
    const float* W2  = (const float*)d_in[7];
    const float* B2  = (const float*)d_in[8];
    const float* L1s = (const float*)d_in[9];
    const float* L1b = (const float*)d_in[10];
    const float* L2s = (const float*)d_in[11];
    const float* L2b = (const float*)d_in[12];
    const float* Fs  = (const float*)d_in[13];
    const float* Fb  = (const float*)d_in[14];

    char* w = (char*)d_ws;
    float*          Xf   = (float*)w;                              // 33.5 MB
    unsigned short* QKVb = (unsigned short*)(w + 33554432);        // 50 MB
    unsigned short* Hb   = (unsigned short*)(w + 83886080);        // 67 MB
    unsigned short* Xb   = (unsigned short*)(w + 150994944);       // 16.8 MB
    unsigned short* ATTb = (unsigned short*)(w + 167772160);       // 16.8 MB
    unsigned short* WB   = (unsigned short*)(w + 184549376);       // 4.7 MB
    float*          PE   = (float*)(w + 189267968);                // 1 MB
    unsigned short* Wib  = WB;
    unsigned short* Wob  = WB + 589824;
    unsigned short* W1b  = WB + 786432;
    unsigned short* W2b  = WB + 1572864;

    cvt_kernel<<<(3 * 768 * 32 + 255) / 256, 256, 0, stream>>>(Wi, Wib, 768, 256, 3);
    cvt_kernel<<<(3 * 256 * 32 + 255) / 256, 256, 0, stream>>>(Wo, Wob, 256, 256, 3);
    cvt_kernel<<<(3 * 1024 * 32 + 255) / 256, 256, 0, stream>>>(W1, W1b, 1024, 256, 3);
    cvt_kernel<<<(3 * 256 * 128 + 255) / 256, 256, 0, stream>>>(W2, W2b, 256, 1024, 3);
    pe_kernel<<<LSEQ, 256, 0, stream>>>(PE);
    embed_kernel<<<dim3(DM / 64, LSEQ / 64, BSZ), 256, 0, stream>>>(F, PE, Xf, Xb);

    for (int i = 0; i < 3; ++i) {
        // QKV = X @ Wi^T + bi -> QKVb (k-chunk bf16)
        gemm_mfma_kernel<<<dim3(MTOK / 128, 768 / 128), 256, 0, stream>>>(
            Xb, Wib + (size_t)i * 196608, Bi + i * 768, QKVb, MTOK, 768, DM, 0);
        // windowed MHA -> ATTb
        attn_mfma_kernel<<<dim3(BSZ * (LSEQ / WIN), NHEAD), 64, 0, stream>>>(QKVb, ATTb);
        // X = LN1( ATT @ Wo^T + bo + X ) -> Xf + Xb
        gemm_ln_kernel<<<MTOK / 64, 256, 0, stream>>>(
            ATTb, Wob + (size_t)i * 65536, Bo + i * DM, Xf,
            L1s + i * DM, L1b + i * DM, Xf, Xb, DM);
        // H = GELU(X @ W1^T + b1) -> Hb
        gemm_mfma_kernel<<<dim3(MTOK / 128, DFF / 128), 256, 0, stream>>>(
            Xb, W1b + (size_t)i * 262144, B1 + i * DFF, Hb, MTOK, DFF, DM, 1);
        // X = LN2( H @ W2^T + b2 + X ) -> Xf + Xb
        gemm_ln_kernel<<<MTOK / 64, 256, 0, stream>>>(
            Hb, W2b + (size_t)i * 262144, B2 + i * DM, Xf,
            L2s + i * DM, L2b + i * DM, Xf, Xb, DFF);
    }

    out_ln_kernel<<<dim3(LSEQ / 64, BSZ), 256, 0, stream>>>(
        Xf, Fs, Fb, (float*)d_out);
}